// Round 6
// baseline (635.555 us; speedup 1.0000x reference)
//
#include <hip/hip_runtime.h>

#define NN 50000
#define DIM 256
#define HH 8
#define TT 2
#define EE 800000
#define HDIM 32
#define NCHUNK 196   // ceil(NN/256)

typedef __attribute__((ext_vector_type(8))) short short8;
typedef __attribute__((ext_vector_type(8))) unsigned short ushort8v;
typedef __attribute__((ext_vector_type(4))) float f32x4;
typedef __attribute__((ext_vector_type(2))) float f32x2;
typedef __attribute__((ext_vector_type(4))) unsigned int u32x4;

__device__ __forceinline__ float bf2f(ushort u) {
    return __uint_as_float(((unsigned)u) << 16);
}
__device__ __forceinline__ ushort f2bf(float f) {
    unsigned u = __float_as_uint(f);
    unsigned r = u + 0x7fffu + ((u >> 16) & 1u);
    return (ushort)(r >> 16);
}

// fp8 e4m3 packed decode (HW): bytes [0:1] (HI=false) or [2:3] (HI=true) of w
template <bool HI>
__device__ __forceinline__ f32x2 cvtpk8(unsigned w) {
    return __builtin_amdgcn_cvt_pk_f32_fp8((int)w, HI);
}

// W (256 x Ncols) row-major -> Wt (Ncols x 256) bf16
__global__ void cvt_wt_k(const float* __restrict__ W, ushort* __restrict__ Wt, int Ncols) {
    int idx = blockIdx.x * blockDim.x + threadIdx.x;
    int total = 256 * Ncols;
    if (idx < total) {
        int k = idx / Ncols;
        int nn = idx - k * Ncols;
        Wt[nn * 256 + k] = f2bf(W[idx]);
    }
}

// ---------- A-stationary MFMA GEMM ----------
// Block = 64 A-rows; A (64x256) staged once in LDS; B read per-fragment from
// global (L2-resident); loop over NCOLS/128 column tiles.
// EPI 0: A=float x; q -> bf16, k/v -> fp8 interleaved groups-of-8.
// EPI 1: A=ushort bf16; fp32 to out with col_base, stride 768.
template <int EPI, int NCOLS>
__global__ __launch_bounds__(256) void gemm2_k(
    const void* __restrict__ Aptr, const ushort* __restrict__ Bt,
    const float* __restrict__ bias,
    ushort* __restrict__ qo, unsigned char* __restrict__ kvo,
    float* __restrict__ outf, int M, int col_base)
{
    __shared__ ushort As[64][264];   // stride 264 ushorts = 528B (16B-aligned rows)
    const int tid = threadIdx.x;
    const int lane = tid & 63;
    const int w = tid >> 6;          // 4 waves: 2M x 2N
    const int wr = w >> 1, wc = w & 1;
    const int lr = lane & 15;
    const int lq = lane >> 4;
    const int m0 = blockIdx.x * 64;

    // ---- stage A (64 x 256) once ----
#pragma unroll
    for (int it = 0; it < 8; ++it) {
        int cid = tid + it * 256;       // 0..2047
        int r = cid >> 5, g = cid & 31; // row, group-of-8
        int gr = m0 + r;
        short8 val = {0, 0, 0, 0, 0, 0, 0, 0};
        if (gr < M) {
            if (EPI == 0) {
                const float* ap = (const float*)Aptr + (size_t)gr * 256 + g * 8;
                float4 v0 = *(const float4*)ap;
                float4 v1 = *(const float4*)(ap + 4);
                val[0] = (short)f2bf(v0.x); val[1] = (short)f2bf(v0.y);
                val[2] = (short)f2bf(v0.z); val[3] = (short)f2bf(v0.w);
                val[4] = (short)f2bf(v1.x); val[5] = (short)f2bf(v1.y);
                val[6] = (short)f2bf(v1.z); val[7] = (short)f2bf(v1.w);
            } else {
                val = *(const short8*)((const ushort*)Aptr + (size_t)gr * 256 + g * 8);
            }
        }
        *(short8*)(&As[r][g * 8]) = val;
    }
    __syncthreads();

    // ---- column-tile loop ----
    for (int ci = 0; ci < NCOLS / 128; ++ci) {
        f32x4 acc[2][4];
#pragma unroll
        for (int mt = 0; mt < 2; ++mt)
#pragma unroll
            for (int nt = 0; nt < 4; ++nt) acc[mt][nt] = (f32x4){0.f, 0.f, 0.f, 0.f};

#pragma unroll 2
        for (int ks = 0; ks < 8; ++ks) {
            int koff = ks * 32 + lq * 8;
            short8 b[4];
#pragma unroll
            for (int nt = 0; nt < 4; ++nt) {
                int coln = ci * 128 + wc * 64 + nt * 16 + lr;
                b[nt] = *(const short8*)(Bt + (size_t)coln * 256 + koff);
            }
            short8 a0 = *(const short8*)(&As[wr * 32 + lr][koff]);
            short8 a1 = *(const short8*)(&As[wr * 32 + 16 + lr][koff]);
#pragma unroll
            for (int nt = 0; nt < 4; ++nt) {
                acc[0][nt] = __builtin_amdgcn_mfma_f32_16x16x32_bf16(a0, b[nt], acc[0][nt], 0, 0, 0);
                acc[1][nt] = __builtin_amdgcn_mfma_f32_16x16x32_bf16(a1, b[nt], acc[1][nt], 0, 0, 0);
            }
        }

        // ---- epilogue for this column tile ----
#pragma unroll
        for (int mt = 0; mt < 2; ++mt) {
            int rowb = m0 + wr * 32 + mt * 16 + (lq << 2);
#pragma unroll
            for (int nt = 0; nt < 4; ++nt) {
                int col = ci * 128 + wc * 64 + nt * 16 + lr;
                float bv = bias[col];
#pragma unroll
                for (int r2 = 0; r2 < 4; ++r2) {
                    int rr = rowb + r2;
                    if (rr < M) {
                        float val = acc[mt][nt][r2] + bv;
                        if (EPI == 0) {
                            int t = col / 768;
                            int rem = col - t * 768;
                            int h = rem / 96;
                            int rem2 = rem - h * 96;
                            int s3 = rem2 >> 5;
                            int hd = rem2 & 31;
                            int d = h * 32 + hd;
                            if (s3 == 0) {
                                qo[((size_t)(t * NN + rr)) * 256 + d] = f2bf(val);
                            } else {
                                unsigned by = ((unsigned)__builtin_amdgcn_cvt_pk_fp8_f32(val, val, 0, false)) & 0xffu;
                                size_t off = ((size_t)(t * NN + rr)) * 512 +
                                             ((size_t)(d >> 3) << 4) + (d & 7) + ((s3 == 2) ? 8 : 0);
                                kvo[off] = (unsigned char)by;
                            }
                        } else {
                            outf[(size_t)rr * 768 + col_base + col] = val;
                        }
                    }
                }
            }
        }
    }
}

// ---------- CSR build ----------
__global__ void count_k(const int* __restrict__ dst, int* __restrict__ cnt) {
    int i = blockIdx.x * blockDim.x + threadIdx.x;
    if (i < TT * EE) {
        int t = i / EE;
        atomicAdd(&cnt[t * NN + dst[i]], 1);
    }
}

__global__ void partial_k(const int* __restrict__ cnt, int* __restrict__ bsum) {
    int b = blockIdx.x;
    int tid = threadIdx.x;
    int t = b / NCHUNK, c = b - t * NCHUNK;
    int i = c * 256 + tid;
    int v = (i < NN) ? cnt[t * NN + i] : 0;
    __shared__ int sh[256];
    sh[tid] = v;
    __syncthreads();
    for (int s = 128; s > 0; s >>= 1) {
        if (tid < s) sh[tid] += sh[tid + s];
        __syncthreads();
    }
    if (tid == 0) bsum[b] = sh[0];
}

__global__ void scanb_k(int* __restrict__ bsum) {
    int tid = threadIdx.x;
    __shared__ int sh[TT][256];
    for (int t = 0; t < TT; ++t) sh[t][tid] = (tid < NCHUNK) ? bsum[t * NCHUNK + tid] : 0;
    __syncthreads();
    for (int off = 1; off < 256; off <<= 1) {
        int v0 = (tid >= off) ? sh[0][tid - off] : 0;
        int v1 = (tid >= off) ? sh[1][tid - off] : 0;
        __syncthreads();
        sh[0][tid] += v0;
        sh[1][tid] += v1;
        __syncthreads();
    }
    for (int t = 0; t < TT; ++t)
        if (tid < NCHUNK) bsum[t * NCHUNK + tid] = (tid == 0) ? 0 : sh[t][tid - 1];
}

__global__ void expand_k(const int* __restrict__ cnt, const int* __restrict__ bsum,
                         int* __restrict__ offs, int* __restrict__ cursor) {
    int b = blockIdx.x;
    int tid = threadIdx.x;
    int t = b / NCHUNK, c = b - t * NCHUNK;
    int i = c * 256 + tid;
    int v = (i < NN) ? cnt[t * NN + i] : 0;
    __shared__ int sh[256];
    sh[tid] = v;
    __syncthreads();
    for (int off = 1; off < 256; off <<= 1) {
        int u = (tid >= off) ? sh[tid - off] : 0;
        __syncthreads();
        sh[tid] += u;
        __syncthreads();
    }
    int incl = sh[tid];
    int base = bsum[b];
    if (i < NN) {
        int o = base + incl - v;
        offs[t * (NN + 1) + i] = o;
        cursor[t * NN + i] = o;
        if (i == NN - 1) offs[t * (NN + 1) + NN] = base + incl;
    }
}

__global__ void scatter_k(const int* __restrict__ dst, const int* __restrict__ src,
                          int* __restrict__ cursor, int* __restrict__ srt) {
    int i = blockIdx.x * blockDim.x + threadIdx.x;
    if (i < TT * EE) {
        int t = i / EE;
        int d = dst[i];
        int pos = atomicAdd(&cursor[t * NN + d], 1);
        srt[(size_t)t * EE + pos] = src[i];
    }
}

// ---------- fused edge attention ----------
__device__ __forceinline__ float f8dot(u32x4 kv, const float* q)
{
    f32x2 c0 = cvtpk8<false>(kv[0]);
    f32x2 c1 = cvtpk8<true>(kv[0]);
    f32x2 c2 = cvtpk8<false>(kv[1]);
    f32x2 c3 = cvtpk8<true>(kv[1]);
    return q[0] * c0[0] + q[1] * c0[1] + q[2] * c1[0] + q[3] * c1[1] +
           q[4] * c2[0] + q[5] * c2[1] + q[6] * c3[0] + q[7] * c3[1];
}

__device__ __forceinline__ void f8acc(float p, u32x4 kv, float* a)
{
    f32x2 c0 = cvtpk8<false>(kv[2]);
    f32x2 c1 = cvtpk8<true>(kv[2]);
    f32x2 c2 = cvtpk8<false>(kv[3]);
    f32x2 c3 = cvtpk8<true>(kv[3]);
    a[0] += p * c0[0]; a[1] += p * c0[1];
    a[2] += p * c1[0]; a[3] += p * c1[1];
    a[4] += p * c2[0]; a[5] += p * c2[1];
    a[6] += p * c3[0]; a[7] += p * c3[1];
}

__global__ __launch_bounds__(256) void attn_k(
    const ushort* __restrict__ q_ws, const unsigned char* __restrict__ kv_ws,
    const int* __restrict__ offs, const int* __restrict__ srt,
    ushort* __restrict__ agg)
{
    int wid = blockIdx.x * 4 + (threadIdx.x >> 6);
    int lane = threadIdx.x & 63;
    int half = lane >> 5;
    int sub = lane & 31;
    int t = wid / NN;
    int node = wid - t * NN;

    const ushort* qp = q_ws + ((size_t)(t * NN + node)) * 256 + sub * 8;
    ushort8v qu = *(const ushort8v*)qp;
    float q[8];
#pragma unroll
    for (int i = 0; i < 8; ++i) q[i] = bf2f(qu[i]);

    int o0 = offs[t * (NN + 1) + node];
    int o1 = offs[t * (NN + 1) + node + 1];
    const int* sp = srt + (size_t)t * EE;
    const unsigned char* kvb = kv_ws + (size_t)t * NN * 512 + sub * 16;

    const float scale = 0.17677669529663689f;
    float zA = 0.f, zB = 0.f;
    float aA[8] = {0.f, 0.f, 0.f, 0.f, 0.f, 0.f, 0.f, 0.f};
    float aB[8] = {0.f, 0.f, 0.f, 0.f, 0.f, 0.f, 0.f, 0.f};

    int j = o0;
    for (; j + 4 <= o1; j += 4) {
        int s0 = sp[j + half];
        int s1 = sp[j + 2 + half];
        u32x4 kv0 = *(const u32x4*)(kvb + (size_t)s0 * 512);
        u32x4 kv1 = *(const u32x4*)(kvb + (size_t)s1 * 512);
        float d0 = f8dot(kv0, q);
        float d1 = f8dot(kv1, q);
        d0 += __shfl_xor(d0, 1); d1 += __shfl_xor(d1, 1);
        d0 += __shfl_xor(d0, 2); d1 += __shfl_xor(d1, 2);
        float p0 = __expf(d0 * scale);
        float p1 = __expf(d1 * scale);
        zA += p0; zB += p1;
        f8acc(p0, kv0, aA);
        f8acc(p1, kv1, aB);
    }
    for (; j < o1; j += 2) {
        int e = j + half;
        int valid = (e < o1) ? 1 : 0;
        int s0 = sp[valid ? e : j];
        u32x4 kv0 = *(const u32x4*)(kvb + (size_t)s0 * 512);
        float d0 = f8dot(kv0, q);
        d0 += __shfl_xor(d0, 1);
        d0 += __shfl_xor(d0, 2);
        float p0 = valid ? __expf(d0 * scale) : 0.f;
        zA += p0;
        f8acc(p0, kv0, aA);
    }

    float z = zA + zB;
    z += __shfl_xor(z, 32);
    float a[8];
#pragma unroll
    for (int i = 0; i < 8; ++i) {
        a[i] = aA[i] + aB[i];
        a[i] += __shfl_xor(a[i], 32);
    }

    if (half == 0) {
        float inv = (z > 0.f) ? 1.0f / z : 0.f;
        ushort8v r;
#pragma unroll
        for (int i = 0; i < 8; ++i) r[i] = f2bf(a[i] * inv);
        *(ushort8v*)(agg + ((size_t)(t * NN + node)) * 256 + sub * 8) = r;
    }
}

// ---------- copy x into out[:, 0:256] ----------
__global__ void xcopy_k(const float* __restrict__ x, float* __restrict__ out) {
    int i = blockIdx.x * blockDim.x + threadIdx.x;
    if (i < NN * 64) {
        int n = i >> 6;
        int c = i & 63;
        float4 v = ((const float4*)x)[i];
        *(float4*)(out + (size_t)n * 768 + c * 4) = v;
    }
}

extern "C" void kernel_launch(void* const* d_in, const int* in_sizes, int n_in,
                              void* d_out, int out_size, void* d_ws, size_t ws_size,
                              hipStream_t stream)
{
    const float* x      = (const float*)d_in[0];
    const float* W_qkv  = (const float*)d_in[1];
    const float* b_qkv  = (const float*)d_in[2];
    const float* W_out  = (const float*)d_in[3];
    const float* b_out  = (const float*)d_in[4];
    const int* edge_src = (const int*)d_in[5];
    const int* edge_dst = (const int*)d_in[6];
    float* out = (float*)d_out;

    char* ws = (char*)d_ws;
    size_t off = 0;
    auto carve = [&](size_t bytes) {
        char* p = ws + off;
        off += (bytes + 255) & ~(size_t)255;
        return p;
    };
    ushort* wqkvt = (ushort*)carve((size_t)1536 * 256 * 2);
    ushort* woutt = (ushort*)carve((size_t)TT * 256 * 256 * 2);
    ushort* q_ws  = (ushort*)carve((size_t)TT * NN * 256 * 2);
    unsigned char* kv_ws = (unsigned char*)carve((size_t)TT * NN * 512);
    ushort* aggb  = (ushort*)carve((size_t)TT * NN * 256 * 2);
    int* cnt    = (int*)carve((size_t)TT * NN * 4);
    int* offs   = (int*)carve((size_t)TT * (NN + 1) * 4);
    int* cursor = (int*)carve((size_t)TT * NN * 4);
    int* srt    = (int*)carve((size_t)TT * EE * 4);
    int* bsum   = (int*)carve((size_t)TT * NCHUNK * 4);

    (void)hipMemsetAsync(cnt, 0, (size_t)TT * NN * 4, stream);

    cvt_wt_k<<<(256 * 1536 + 255) / 256, 256, 0, stream>>>(W_qkv, wqkvt, 1536);
    for (int t = 0; t < TT; ++t)
        cvt_wt_k<<<(256 * 256 + 255) / 256, 256, 0, stream>>>(W_out + (size_t)t * 65536,
                                                              woutt + (size_t)t * 65536, 256);

    gemm2_k<0, 1536><<<782, 256, 0, stream>>>(x, wqkvt, b_qkv, q_ws, kv_ws,
                                              nullptr, NN, 0);

    count_k<<<(TT * EE + 255) / 256, 256, 0, stream>>>(edge_dst, cnt);
    partial_k<<<TT * NCHUNK, 256, 0, stream>>>(cnt, bsum);
    scanb_k<<<1, 256, 0, stream>>>(bsum);
    expand_k<<<TT * NCHUNK, 256, 0, stream>>>(cnt, bsum, offs, cursor);
    scatter_k<<<(TT * EE + 255) / 256, 256, 0, stream>>>(edge_dst, edge_src, cursor, srt);

    attn_k<<<(NN * TT) / 4, 256, 0, stream>>>(q_ws, kv_ws, offs, srt, aggb);

    for (int t = 0; t < TT; ++t)
        gemm2_k<1, 256><<<782, 256, 0, stream>>>(aggb + (size_t)t * NN * 256,
                                                 woutt + (size_t)t * 65536,
                                                 b_out + (size_t)t * 256,
                                                 nullptr, nullptr,
                                                 out, NN, 256 + t * 256);

    xcopy_k<<<(NN * 64 + 255) / 256, 256, 0, stream>>>(x, out);
}

// Round 7
// 515.144 us; speedup vs baseline: 1.2337x; 1.2337x over previous
//
#include <hip/hip_runtime.h>

#define NN 50000
#define DIM 256
#define HH 8
#define TT 2
#define EE 800000
#define HDIM 32
#define NCHUNK 196   // ceil(NN/256)

typedef __attribute__((ext_vector_type(8))) short short8;
typedef __attribute__((ext_vector_type(8))) unsigned short ushort8v;
typedef __attribute__((ext_vector_type(4))) float f32x4;
typedef __attribute__((ext_vector_type(2))) float f32x2;
typedef __attribute__((ext_vector_type(4))) unsigned int u32x4;

typedef __attribute__((address_space(3))) unsigned int u32_lds;
typedef __attribute__((address_space(1))) const unsigned int u32_glb;

__device__ __forceinline__ float bf2f(ushort u) {
    return __uint_as_float(((unsigned)u) << 16);
}
__device__ __forceinline__ ushort f2bf(float f) {
    unsigned u = __float_as_uint(f);
    unsigned r = u + 0x7fffu + ((u >> 16) & 1u);
    return (ushort)(r >> 16);
}

// fp8 e4m3 packed decode (HW): bytes [0:1] (HI=false) or [2:3] (HI=true) of w
template <bool HI>
__device__ __forceinline__ f32x2 cvtpk8(unsigned w) {
    return __builtin_amdgcn_cvt_pk_f32_fp8((int)w, HI);
}

// ---------- converts ----------
__global__ void cvt_x_k(const float* __restrict__ x, ushort* __restrict__ xb, int n4) {
    int i = blockIdx.x * blockDim.x + threadIdx.x;
    if (i < n4) {
        float4 v = ((const float4*)x)[i];
        ushort4 o;
        o.x = f2bf(v.x); o.y = f2bf(v.y); o.z = f2bf(v.z); o.w = f2bf(v.w);
        ((ushort4*)xb)[i] = o;
    }
}

// W (256 x Ncols) row-major -> Wt (Ncols x 256) bf16
__global__ void cvt_wt_k(const float* __restrict__ W, ushort* __restrict__ Wt, int Ncols) {
    int idx = blockIdx.x * blockDim.x + threadIdx.x;
    int total = 256 * Ncols;
    if (idx < total) {
        int k = idx / Ncols;
        int nn = idx - k * Ncols;
        Wt[nn * 256 + k] = f2bf(W[idx]);
    }
}

// ---------- m97-style MFMA GEMM: 128x128 tile, BK=64, global_load_lds + XOR swizzle ----
// C(M x gridDim.y*128) = A(M x 256, bf16) @ Bt(ncols x 256, bf16)^T + bias
// LDS tiles linear [128 rows][8 slots of 16B]; content slot s holds global slot s^(row&7).
// EPI 0: q -> bf16, k/v -> fp8 interleaved groups-of-8.  EPI 1: fp32 to out (stride 768).
template <int EPI>
__global__ __launch_bounds__(256) void gemm3_k(
    const ushort* __restrict__ A, const ushort* __restrict__ Bt,
    const float* __restrict__ bias,
    ushort* __restrict__ qo, unsigned char* __restrict__ kvo,
    float* __restrict__ outf, int M, int col_base)
{
    __shared__ ushort As[128 * 64];
    __shared__ ushort Bs[128 * 64];
    const int tid = threadIdx.x;
    const int lane = tid & 63;
    const int w = tid >> 6;          // 4 waves: 2M x 2N
    const int wr = w >> 1, wc = w & 1;
    const int lr = lane & 15;
    const int lq = lane >> 4;
    const int m0 = blockIdx.x * 128;
    const int n0 = blockIdx.y * 128;

    f32x4 acc[4][4];
#pragma unroll
    for (int mt = 0; mt < 4; ++mt)
#pragma unroll
        for (int nt = 0; nt < 4; ++nt) acc[mt][nt] = (f32x4){0.f, 0.f, 0.f, 0.f};

    for (int ks = 0; ks < 256; ks += 64) {
        // ---- stage A,B tiles: 16KB each via global_load_lds width=16 ----
#pragma unroll
        for (int it = 0; it < 4; ++it) {
            int u = tid + it * 256;          // 0..1023: row=u>>3, slot=u&7
            int r = u >> 3, s = u & 7;
            int ss = (s ^ (r & 7)) << 3;     // pre-swizzled source slot (elements)
            const ushort* srcA = A + (size_t)(m0 + r) * 256 + ks + ss;
            __builtin_amdgcn_global_load_lds((u32_glb*)srcA,
                (u32_lds*)((char*)As + (u << 4)), 16, 0, 0);
            const ushort* srcB = Bt + (size_t)(n0 + r) * 256 + ks + ss;
            __builtin_amdgcn_global_load_lds((u32_glb*)srcB,
                (u32_lds*)((char*)Bs + (u << 4)), 16, 0, 0);
        }
        __syncthreads();

#pragma unroll
        for (int ku = 0; ku < 2; ++ku) {
            short8 a[4], b[4];
#pragma unroll
            for (int mt = 0; mt < 4; ++mt) {
                int row = wr * 64 + mt * 16 + lr;
                int s = ku * 4 + lq;
                a[mt] = *(const short8*)((const char*)As + row * 128 + (((s ^ (row & 7)) & 7) << 4));
            }
#pragma unroll
            for (int nt = 0; nt < 4; ++nt) {
                int row = wc * 64 + nt * 16 + lr;
                int s = ku * 4 + lq;
                b[nt] = *(const short8*)((const char*)Bs + row * 128 + (((s ^ (row & 7)) & 7) << 4));
            }
#pragma unroll
            for (int mt = 0; mt < 4; ++mt)
#pragma unroll
                for (int nt = 0; nt < 4; ++nt)
                    acc[mt][nt] = __builtin_amdgcn_mfma_f32_16x16x32_bf16(a[mt], b[nt], acc[mt][nt], 0, 0, 0);
        }
        __syncthreads();
    }

    // ---- epilogue ----
#pragma unroll
    for (int mt = 0; mt < 4; ++mt) {
        int rowb = m0 + wr * 64 + mt * 16 + (lq << 2);
#pragma unroll
        for (int nt = 0; nt < 4; ++nt) {
            int col = n0 + wc * 64 + nt * 16 + lr;
            float bv = bias[col];
#pragma unroll
            for (int r2 = 0; r2 < 4; ++r2) {
                int rr = rowb + r2;
                if (rr < M) {
                    float val = acc[mt][nt][r2] + bv;
                    if (EPI == 0) {
                        int t = col / 768;
                        int rem = col - t * 768;
                        int h = rem / 96;
                        int rem2 = rem - h * 96;
                        int s3 = rem2 >> 5;
                        int hd = rem2 & 31;
                        int d = h * 32 + hd;
                        if (s3 == 0) {
                            qo[((size_t)(t * NN + rr)) * 256 + d] = f2bf(val);
                        } else {
                            unsigned by = ((unsigned)__builtin_amdgcn_cvt_pk_fp8_f32(val, val, 0, false)) & 0xffu;
                            size_t off = ((size_t)(t * NN + rr)) * 512 +
                                         ((size_t)(d >> 3) << 4) + (d & 7) + ((s3 == 2) ? 8 : 0);
                            kvo[off] = (unsigned char)by;
                        }
                    } else {
                        outf[(size_t)rr * 768 + col_base + col] = val;
                    }
                }
            }
        }
    }
}

// ---------- CSR build ----------
__global__ void count_k(const int* __restrict__ dst, int* __restrict__ cnt) {
    int i = blockIdx.x * blockDim.x + threadIdx.x;
    if (i < TT * EE) {
        int t = i / EE;
        atomicAdd(&cnt[t * NN + dst[i]], 1);
    }
}

__global__ void partial_k(const int* __restrict__ cnt, int* __restrict__ bsum) {
    int b = blockIdx.x;
    int tid = threadIdx.x;
    int t = b / NCHUNK, c = b - t * NCHUNK;
    int i = c * 256 + tid;
    int v = (i < NN) ? cnt[t * NN + i] : 0;
    __shared__ int sh[256];
    sh[tid] = v;
    __syncthreads();
    for (int s = 128; s > 0; s >>= 1) {
        if (tid < s) sh[tid] += sh[tid + s];
        __syncthreads();
    }
    if (tid == 0) bsum[b] = sh[0];
}

__global__ void scanb_k(int* __restrict__ bsum) {
    int tid = threadIdx.x;
    __shared__ int sh[TT][256];
    for (int t = 0; t < TT; ++t) sh[t][tid] = (tid < NCHUNK) ? bsum[t * NCHUNK + tid] : 0;
    __syncthreads();
    for (int off = 1; off < 256; off <<= 1) {
        int v0 = (tid >= off) ? sh[0][tid - off] : 0;
        int v1 = (tid >= off) ? sh[1][tid - off] : 0;
        __syncthreads();
        sh[0][tid] += v0;
        sh[1][tid] += v1;
        __syncthreads();
    }
    for (int t = 0; t < TT; ++t)
        if (tid < NCHUNK) bsum[t * NCHUNK + tid] = (tid == 0) ? 0 : sh[t][tid - 1];
}

__global__ void expand_k(const int* __restrict__ cnt, const int* __restrict__ bsum,
                         int* __restrict__ offs, int* __restrict__ cursor) {
    int b = blockIdx.x;
    int tid = threadIdx.x;
    int t = b / NCHUNK, c = b - t * NCHUNK;
    int i = c * 256 + tid;
    int v = (i < NN) ? cnt[t * NN + i] : 0;
    __shared__ int sh[256];
    sh[tid] = v;
    __syncthreads();
    for (int off = 1; off < 256; off <<= 1) {
        int u = (tid >= off) ? sh[tid - off] : 0;
        __syncthreads();
        sh[tid] += u;
        __syncthreads();
    }
    int incl = sh[tid];
    int base = bsum[b];
    if (i < NN) {
        int o = base + incl - v;
        offs[t * (NN + 1) + i] = o;
        cursor[t * NN + i] = o;
        if (i == NN - 1) offs[t * (NN + 1) + NN] = base + incl;
    }
}

__global__ void scatter_k(const int* __restrict__ dst, const int* __restrict__ src,
                          int* __restrict__ cursor, int* __restrict__ srt) {
    int i = blockIdx.x * blockDim.x + threadIdx.x;
    if (i < TT * EE) {
        int t = i / EE;
        int d = dst[i];
        int pos = atomicAdd(&cursor[t * NN + d], 1);
        srt[(size_t)t * EE + pos] = src[i];
    }
}

// ---------- fused edge attention ----------
__device__ __forceinline__ float f8dot(u32x4 kv, const float* q)
{
    f32x2 c0 = cvtpk8<false>(kv[0]);
    f32x2 c1 = cvtpk8<true>(kv[0]);
    f32x2 c2 = cvtpk8<false>(kv[1]);
    f32x2 c3 = cvtpk8<true>(kv[1]);
    return q[0] * c0[0] + q[1] * c0[1] + q[2] * c1[0] + q[3] * c1[1] +
           q[4] * c2[0] + q[5] * c2[1] + q[6] * c3[0] + q[7] * c3[1];
}

__device__ __forceinline__ void f8acc(float p, u32x4 kv, float* a)
{
    f32x2 c0 = cvtpk8<false>(kv[2]);
    f32x2 c1 = cvtpk8<true>(kv[2]);
    f32x2 c2 = cvtpk8<false>(kv[3]);
    f32x2 c3 = cvtpk8<true>(kv[3]);
    a[0] += p * c0[0]; a[1] += p * c0[1];
    a[2] += p * c1[0]; a[3] += p * c1[1];
    a[4] += p * c2[0]; a[5] += p * c2[1];
    a[6] += p * c3[0]; a[7] += p * c3[1];
}

__global__ __launch_bounds__(256) void attn_k(
    const ushort* __restrict__ q_ws, const unsigned char* __restrict__ kv_ws,
    const int* __restrict__ offs, const int* __restrict__ srt,
    ushort* __restrict__ agg)
{
    int wid = blockIdx.x * 4 + (threadIdx.x >> 6);
    int lane = threadIdx.x & 63;
    int half = lane >> 5;
    int sub = lane & 31;
    int t = wid / NN;
    int node = wid - t * NN;

    const ushort* qp = q_ws + ((size_t)(t * NN + node)) * 256 + sub * 8;
    ushort8v qu = *(const ushort8v*)qp;
    float q[8];
#pragma unroll
    for (int i = 0; i < 8; ++i) q[i] = bf2f(qu[i]);

    int o0 = offs[t * (NN + 1) + node];
    int o1 = offs[t * (NN + 1) + node + 1];
    const int* sp = srt + (size_t)t * EE;
    const unsigned char* kvb = kv_ws + (size_t)t * NN * 512 + sub * 16;

    const float scale = 0.17677669529663689f;
    float zA = 0.f, zB = 0.f;
    float aA[8] = {0.f, 0.f, 0.f, 0.f, 0.f, 0.f, 0.f, 0.f};
    float aB[8] = {0.f, 0.f, 0.f, 0.f, 0.f, 0.f, 0.f, 0.f};

    int j = o0;
    for (; j + 4 <= o1; j += 4) {
        int s0 = sp[j + half];
        int s1 = sp[j + 2 + half];
        u32x4 kv0 = *(const u32x4*)(kvb + (size_t)s0 * 512);
        u32x4 kv1 = *(const u32x4*)(kvb + (size_t)s1 * 512);
        float d0 = f8dot(kv0, q);
        float d1 = f8dot(kv1, q);
        d0 += __shfl_xor(d0, 1); d1 += __shfl_xor(d1, 1);
        d0 += __shfl_xor(d0, 2); d1 += __shfl_xor(d1, 2);
        float p0 = __expf(d0 * scale);
        float p1 = __expf(d1 * scale);
        zA += p0; zB += p1;
        f8acc(p0, kv0, aA);
        f8acc(p1, kv1, aB);
    }
    for (; j < o1; j += 2) {
        int e = j + half;
        int valid = (e < o1) ? 1 : 0;
        int s0 = sp[valid ? e : j];
        u32x4 kv0 = *(const u32x4*)(kvb + (size_t)s0 * 512);
        float d0 = f8dot(kv0, q);
        d0 += __shfl_xor(d0, 1);
        d0 += __shfl_xor(d0, 2);
        float p0 = valid ? __expf(d0 * scale) : 0.f;
        zA += p0;
        f8acc(p0, kv0, aA);
    }

    float z = zA + zB;
    z += __shfl_xor(z, 32);
    float a[8];
#pragma unroll
    for (int i = 0; i < 8; ++i) {
        a[i] = aA[i] + aB[i];
        a[i] += __shfl_xor(a[i], 32);
    }

    if (half == 0) {
        float inv = (z > 0.f) ? 1.0f / z : 0.f;
        ushort8v r;
#pragma unroll
        for (int i = 0; i < 8; ++i) r[i] = f2bf(a[i] * inv);
        *(ushort8v*)(agg + ((size_t)(t * NN + node)) * 256 + sub * 8) = r;
    }
}

// ---------- copy x into out[:, 0:256] ----------
__global__ void xcopy_k(const float* __restrict__ x, float* __restrict__ out) {
    int i = blockIdx.x * blockDim.x + threadIdx.x;
    if (i < NN * 64) {
        int n = i >> 6;
        int c = i & 63;
        float4 v = ((const float4*)x)[i];
        *(float4*)(out + (size_t)n * 768 + c * 4) = v;
    }
}

extern "C" void kernel_launch(void* const* d_in, const int* in_sizes, int n_in,
                              void* d_out, int out_size, void* d_ws, size_t ws_size,
                              hipStream_t stream)
{
    const float* x      = (const float*)d_in[0];
    const float* W_qkv  = (const float*)d_in[1];
    const float* b_qkv  = (const float*)d_in[2];
    const float* W_out  = (const float*)d_in[3];
    const float* b_out  = (const float*)d_in[4];
    const int* edge_src = (const int*)d_in[5];
    const int* edge_dst = (const int*)d_in[6];
    float* out = (float*)d_out;

    char* ws = (char*)d_ws;
    size_t off = 0;
    auto carve = [&](size_t bytes) {
        char* p = ws + off;
        off += (bytes + 255) & ~(size_t)255;
        return p;
    };
    ushort* xb    = (ushort*)carve((size_t)NN * DIM * 2);
    ushort* wqkvt = (ushort*)carve((size_t)1536 * 256 * 2);
    ushort* woutt = (ushort*)carve((size_t)TT * 256 * 256 * 2);
    ushort* q_ws  = (ushort*)carve((size_t)TT * NN * 256 * 2);
    unsigned char* kv_ws = (unsigned char*)carve((size_t)TT * NN * 512);
    ushort* aggb  = (ushort*)carve((size_t)TT * NN * 256 * 2);
    int* cnt    = (int*)carve((size_t)TT * NN * 4);
    int* offs   = (int*)carve((size_t)TT * (NN + 1) * 4);
    int* cursor = (int*)carve((size_t)TT * NN * 4);
    int* srt    = (int*)carve((size_t)TT * EE * 4);
    int* bsum   = (int*)carve((size_t)TT * NCHUNK * 4);

    (void)hipMemsetAsync(cnt, 0, (size_t)TT * NN * 4, stream);

    cvt_x_k<<<(NN * DIM / 4 + 255) / 256, 256, 0, stream>>>(x, xb, NN * DIM / 4);
    cvt_wt_k<<<(256 * 1536 + 255) / 256, 256, 0, stream>>>(W_qkv, wqkvt, 1536);
    for (int t = 0; t < TT; ++t)
        cvt_wt_k<<<(256 * 256 + 255) / 256, 256, 0, stream>>>(W_out + (size_t)t * 65536,
                                                              woutt + (size_t)t * 65536, 256);

    gemm3_k<0><<<dim3(391, 12), 256, 0, stream>>>(xb, wqkvt, b_qkv, q_ws, kv_ws,
                                                  nullptr, NN, 0);

    count_k<<<(TT * EE + 255) / 256, 256, 0, stream>>>(edge_dst, cnt);
    partial_k<<<TT * NCHUNK, 256, 0, stream>>>(cnt, bsum);
    scanb_k<<<1, 256, 0, stream>>>(bsum);
    expand_k<<<TT * NCHUNK, 256, 0, stream>>>(cnt, bsum, offs, cursor);
    scatter_k<<<(TT * EE + 255) / 256, 256, 0, stream>>>(edge_dst, edge_src, cursor, srt);

    attn_k<<<(NN * TT) / 4, 256, 0, stream>>>(q_ws, kv_ws, offs, srt, aggb);

    for (int t = 0; t < TT; ++t)
        gemm3_k<1><<<dim3(391, 2), 256, 0, stream>>>(aggb + (size_t)t * NN * 256,
                                                     woutt + (size_t)t * 65536,
                                                     b_out + (size_t)t * 256,
                                                     nullptr, nullptr,
                                                     out, NN, 256 + t * 256);

    xcopy_k<<<(NN * 64 + 255) / 256, 256, 0, stream>>>(x, out);
}

// Round 8
// 512.980 us; speedup vs baseline: 1.2389x; 1.0042x over previous
//
#include <hip/hip_runtime.h>

#define NN 50000
#define DIM 256
#define HH 8
#define TT 2
#define EE 800000
#define HDIM 32
#define NCHUNK 196   // ceil(NN/256)

typedef __attribute__((ext_vector_type(8))) short short8;
typedef __attribute__((ext_vector_type(8))) unsigned short ushort8v;
typedef __attribute__((ext_vector_type(4))) float f32x4;
typedef __attribute__((ext_vector_type(2))) float f32x2;
typedef __attribute__((ext_vector_type(4))) unsigned int u32x4;

typedef __attribute__((address_space(3))) unsigned int u32_lds;
typedef __attribute__((address_space(1))) const unsigned int u32_glb;

__device__ __forceinline__ float bf2f(ushort u) {
    return __uint_as_float(((unsigned)u) << 16);
}
__device__ __forceinline__ ushort f2bf(float f) {
    unsigned u = __float_as_uint(f);
    unsigned r = u + 0x7fffu + ((u >> 16) & 1u);
    return (ushort)(r >> 16);
}

// fp8 e4m3 packed decode (HW): bytes [0:1] (HI=false) or [2:3] (HI=true) of w
template <bool HI>
__device__ __forceinline__ f32x2 cvtpk8(unsigned w) {
    return __builtin_amdgcn_cvt_pk_f32_fp8((int)w, HI);
}

// ---------- converts ----------
__global__ void cvt_x_k(const float* __restrict__ x, ushort* __restrict__ xb, int n4) {
    int i = blockIdx.x * blockDim.x + threadIdx.x;
    if (i < n4) {
        float4 v = ((const float4*)x)[i];
        ushort4 o;
        o.x = f2bf(v.x); o.y = f2bf(v.y); o.z = f2bf(v.z); o.w = f2bf(v.w);
        ((ushort4*)xb)[i] = o;
    }
}

// W (256 x Ncols) row-major -> Wt (Ncols x 256) bf16
__global__ void cvt_wt_k(const float* __restrict__ W, ushort* __restrict__ Wt, int Ncols) {
    int idx = blockIdx.x * blockDim.x + threadIdx.x;
    int total = 256 * Ncols;
    if (idx < total) {
        int k = idx / Ncols;
        int nn = idx - k * Ncols;
        Wt[nn * 256 + k] = f2bf(W[idx]);
    }
}

// ---------- m97-style MFMA GEMM: 128x128 tile, BK=64, global_load_lds + XOR swizzle ----
template <int EPI>
__global__ __launch_bounds__(256) void gemm3_k(
    const ushort* __restrict__ A, const ushort* __restrict__ Bt,
    const float* __restrict__ bias,
    ushort* __restrict__ qo, unsigned char* __restrict__ kvo,
    float* __restrict__ outf, int M, int col_base)
{
    __shared__ ushort As[128 * 64];
    __shared__ ushort Bs[128 * 64];
    const int tid = threadIdx.x;
    const int lane = tid & 63;
    const int w = tid >> 6;          // 4 waves: 2M x 2N
    const int wr = w >> 1, wc = w & 1;
    const int lr = lane & 15;
    const int lq = lane >> 4;
    const int m0 = blockIdx.x * 128;
    const int n0 = blockIdx.y * 128;

    f32x4 acc[4][4];
#pragma unroll
    for (int mt = 0; mt < 4; ++mt)
#pragma unroll
        for (int nt = 0; nt < 4; ++nt) acc[mt][nt] = (f32x4){0.f, 0.f, 0.f, 0.f};

    for (int ks = 0; ks < 256; ks += 64) {
#pragma unroll
        for (int it = 0; it < 4; ++it) {
            int u = tid + it * 256;          // 0..1023: row=u>>3, slot=u&7
            int r = u >> 3, s = u & 7;
            int ss = (s ^ (r & 7)) << 3;     // pre-swizzled source slot (elements)
            const ushort* srcA = A + (size_t)(m0 + r) * 256 + ks + ss;
            __builtin_amdgcn_global_load_lds((u32_glb*)srcA,
                (u32_lds*)((char*)As + (u << 4)), 16, 0, 0);
            const ushort* srcB = Bt + (size_t)(n0 + r) * 256 + ks + ss;
            __builtin_amdgcn_global_load_lds((u32_glb*)srcB,
                (u32_lds*)((char*)Bs + (u << 4)), 16, 0, 0);
        }
        __syncthreads();

#pragma unroll
        for (int ku = 0; ku < 2; ++ku) {
            short8 a[4], b[4];
#pragma unroll
            for (int mt = 0; mt < 4; ++mt) {
                int row = wr * 64 + mt * 16 + lr;
                int s = ku * 4 + lq;
                a[mt] = *(const short8*)((const char*)As + row * 128 + (((s ^ (row & 7)) & 7) << 4));
            }
#pragma unroll
            for (int nt = 0; nt < 4; ++nt) {
                int row = wc * 64 + nt * 16 + lr;
                int s = ku * 4 + lq;
                b[nt] = *(const short8*)((const char*)Bs + row * 128 + (((s ^ (row & 7)) & 7) << 4));
            }
#pragma unroll
            for (int mt = 0; mt < 4; ++mt)
#pragma unroll
                for (int nt = 0; nt < 4; ++nt)
                    acc[mt][nt] = __builtin_amdgcn_mfma_f32_16x16x32_bf16(a[mt], b[nt], acc[mt][nt], 0, 0, 0);
        }
        __syncthreads();
    }

#pragma unroll
    for (int mt = 0; mt < 4; ++mt) {
        int rowb = m0 + wr * 64 + mt * 16 + (lq << 2);
#pragma unroll
        for (int nt = 0; nt < 4; ++nt) {
            int col = n0 + wc * 64 + nt * 16 + lr;
            float bv = bias[col];
#pragma unroll
            for (int r2 = 0; r2 < 4; ++r2) {
                int rr = rowb + r2;
                if (rr < M) {
                    float val = acc[mt][nt][r2] + bv;
                    if (EPI == 0) {
                        int t = col / 768;
                        int rem = col - t * 768;
                        int h = rem / 96;
                        int rem2 = rem - h * 96;
                        int s3 = rem2 >> 5;
                        int hd = rem2 & 31;
                        int d = h * 32 + hd;
                        if (s3 == 0) {
                            qo[((size_t)(t * NN + rr)) * 256 + d] = f2bf(val);
                        } else {
                            unsigned by = ((unsigned)__builtin_amdgcn_cvt_pk_fp8_f32(val, val, 0, false)) & 0xffu;
                            size_t off = ((size_t)(t * NN + rr)) * 512 +
                                         ((size_t)(d >> 3) << 4) + (d & 7) + ((s3 == 2) ? 8 : 0);
                            kvo[off] = (unsigned char)by;
                        }
                    } else {
                        outf[(size_t)rr * 768 + col_base + col] = val;
                    }
                }
            }
        }
    }
}

// ---------- CSR build (8 edges/thread for latency hiding) ----------
__global__ void count_k(const int* __restrict__ dst, int* __restrict__ cnt) {
    int g = blockIdx.x * blockDim.x + threadIdx.x;
    int i0 = g * 8;
    if (i0 >= TT * EE) return;
    int t = i0 / EE;                 // EE % 8 == 0 -> uniform within group
    int* c = cnt + t * NN;
    int4 d0 = *(const int4*)(dst + i0);
    int4 d1 = *(const int4*)(dst + i0 + 4);
    atomicAdd(&c[d0.x], 1); atomicAdd(&c[d0.y], 1);
    atomicAdd(&c[d0.z], 1); atomicAdd(&c[d0.w], 1);
    atomicAdd(&c[d1.x], 1); atomicAdd(&c[d1.y], 1);
    atomicAdd(&c[d1.z], 1); atomicAdd(&c[d1.w], 1);
}

__global__ void partial_k(const int* __restrict__ cnt, int* __restrict__ bsum) {
    int b = blockIdx.x;
    int tid = threadIdx.x;
    int t = b / NCHUNK, c = b - t * NCHUNK;
    int i = c * 256 + tid;
    int v = (i < NN) ? cnt[t * NN + i] : 0;
    __shared__ int sh[256];
    sh[tid] = v;
    __syncthreads();
    for (int s = 128; s > 0; s >>= 1) {
        if (tid < s) sh[tid] += sh[tid + s];
        __syncthreads();
    }
    if (tid == 0) bsum[b] = sh[0];
}

__global__ void scanb_k(int* __restrict__ bsum) {
    int tid = threadIdx.x;
    __shared__ int sh[TT][256];
    for (int t = 0; t < TT; ++t) sh[t][tid] = (tid < NCHUNK) ? bsum[t * NCHUNK + tid] : 0;
    __syncthreads();
    for (int off = 1; off < 256; off <<= 1) {
        int v0 = (tid >= off) ? sh[0][tid - off] : 0;
        int v1 = (tid >= off) ? sh[1][tid - off] : 0;
        __syncthreads();
        sh[0][tid] += v0;
        sh[1][tid] += v1;
        __syncthreads();
    }
    for (int t = 0; t < TT; ++t)
        if (tid < NCHUNK) bsum[t * NCHUNK + tid] = (tid == 0) ? 0 : sh[t][tid - 1];
}

__global__ void expand_k(const int* __restrict__ cnt, const int* __restrict__ bsum,
                         int* __restrict__ offs, int* __restrict__ cursor) {
    int b = blockIdx.x;
    int tid = threadIdx.x;
    int t = b / NCHUNK, c = b - t * NCHUNK;
    int i = c * 256 + tid;
    int v = (i < NN) ? cnt[t * NN + i] : 0;
    __shared__ int sh[256];
    sh[tid] = v;
    __syncthreads();
    for (int off = 1; off < 256; off <<= 1) {
        int u = (tid >= off) ? sh[tid - off] : 0;
        __syncthreads();
        sh[tid] += u;
        __syncthreads();
    }
    int incl = sh[tid];
    int base = bsum[b];
    if (i < NN) {
        int o = base + incl - v;
        offs[t * (NN + 1) + i] = o;
        cursor[t * NN + i] = o;
        if (i == NN - 1) offs[t * (NN + 1) + NN] = base + incl;
    }
}

__global__ void scatter_k(const int* __restrict__ dst, const int* __restrict__ src,
                          int* __restrict__ cursor, int* __restrict__ srt) {
    int g = blockIdx.x * blockDim.x + threadIdx.x;
    int i0 = g * 8;
    if (i0 >= TT * EE) return;
    int t = i0 / EE;                 // EE % 8 == 0 -> uniform within group
    int* cur = cursor + t * NN;
    int* sr = srt + (size_t)t * EE;
    int4 d0 = *(const int4*)(dst + i0);
    int4 d1 = *(const int4*)(dst + i0 + 4);
    int4 s0 = *(const int4*)(src + i0);
    int4 s1 = *(const int4*)(src + i0 + 4);
    int p0 = atomicAdd(&cur[d0.x], 1);
    int p1 = atomicAdd(&cur[d0.y], 1);
    int p2 = atomicAdd(&cur[d0.z], 1);
    int p3 = atomicAdd(&cur[d0.w], 1);
    int p4 = atomicAdd(&cur[d1.x], 1);
    int p5 = atomicAdd(&cur[d1.y], 1);
    int p6 = atomicAdd(&cur[d1.z], 1);
    int p7 = atomicAdd(&cur[d1.w], 1);
    sr[p0] = s0.x; sr[p1] = s0.y; sr[p2] = s0.z; sr[p3] = s0.w;
    sr[p4] = s1.x; sr[p5] = s1.y; sr[p6] = s1.z; sr[p7] = s1.w;
}

// ---------- fused edge attention ----------
__device__ __forceinline__ float f8dot(u32x4 kv, const float* q)
{
    f32x2 c0 = cvtpk8<false>(kv[0]);
    f32x2 c1 = cvtpk8<true>(kv[0]);
    f32x2 c2 = cvtpk8<false>(kv[1]);
    f32x2 c3 = cvtpk8<true>(kv[1]);
    return q[0] * c0[0] + q[1] * c0[1] + q[2] * c1[0] + q[3] * c1[1] +
           q[4] * c2[0] + q[5] * c2[1] + q[6] * c3[0] + q[7] * c3[1];
}

__device__ __forceinline__ void f8acc(float p, u32x4 kv, float* a)
{
    f32x2 c0 = cvtpk8<false>(kv[2]);
    f32x2 c1 = cvtpk8<true>(kv[2]);
    f32x2 c2 = cvtpk8<false>(kv[3]);
    f32x2 c3 = cvtpk8<true>(kv[3]);
    a[0] += p * c0[0]; a[1] += p * c0[1];
    a[2] += p * c1[0]; a[3] += p * c1[1];
    a[4] += p * c2[0]; a[5] += p * c2[1];
    a[6] += p * c3[0]; a[7] += p * c3[1];
}

__global__ __launch_bounds__(256) void attn_k(
    const ushort* __restrict__ q_ws, const unsigned char* __restrict__ kv_ws,
    const int* __restrict__ offs, const int* __restrict__ srt,
    ushort* __restrict__ agg)
{
    int wid = blockIdx.x * 4 + (threadIdx.x >> 6);
    int lane = threadIdx.x & 63;
    int half = lane >> 5;
    int sub = lane & 31;
    int t = wid / NN;
    int node = wid - t * NN;

    const ushort* qp = q_ws + ((size_t)(t * NN + node)) * 256 + sub * 8;
    ushort8v qu = *(const ushort8v*)qp;
    float q[8];
#pragma unroll
    for (int i = 0; i < 8; ++i) q[i] = bf2f(qu[i]);

    int o0 = offs[t * (NN + 1) + node];
    int o1 = offs[t * (NN + 1) + node + 1];
    const int* sp = srt + (size_t)t * EE;
    const unsigned char* kvb = kv_ws + (size_t)t * NN * 512 + sub * 16;

    const float scale = 0.17677669529663689f;
    float zA = 0.f, zB = 0.f;
    float aA[8] = {0.f, 0.f, 0.f, 0.f, 0.f, 0.f, 0.f, 0.f};
    float aB[8] = {0.f, 0.f, 0.f, 0.f, 0.f, 0.f, 0.f, 0.f};

    int j = o0;
    for (; j + 4 <= o1; j += 4) {
        int s0 = sp[j + half];
        int s1 = sp[j + 2 + half];
        u32x4 kv0 = *(const u32x4*)(kvb + (size_t)s0 * 512);
        u32x4 kv1 = *(const u32x4*)(kvb + (size_t)s1 * 512);
        float d0 = f8dot(kv0, q);
        float d1 = f8dot(kv1, q);
        d0 += __shfl_xor(d0, 1); d1 += __shfl_xor(d1, 1);
        d0 += __shfl_xor(d0, 2); d1 += __shfl_xor(d1, 2);
        float p0 = __expf(d0 * scale);
        float p1 = __expf(d1 * scale);
        zA += p0; zB += p1;
        f8acc(p0, kv0, aA);
        f8acc(p1, kv1, aB);
    }
    for (; j < o1; j += 2) {
        int e = j + half;
        int valid = (e < o1) ? 1 : 0;
        int s0 = sp[valid ? e : j];
        u32x4 kv0 = *(const u32x4*)(kvb + (size_t)s0 * 512);
        float d0 = f8dot(kv0, q);
        d0 += __shfl_xor(d0, 1);
        d0 += __shfl_xor(d0, 2);
        float p0 = valid ? __expf(d0 * scale) : 0.f;
        zA += p0;
        f8acc(p0, kv0, aA);
    }

    float z = zA + zB;
    z += __shfl_xor(z, 32);
    float a[8];
#pragma unroll
    for (int i = 0; i < 8; ++i) {
        a[i] = aA[i] + aB[i];
        a[i] += __shfl_xor(a[i], 32);
    }

    if (half == 0) {
        float inv = (z > 0.f) ? 1.0f / z : 0.f;
        ushort8v r;
#pragma unroll
        for (int i = 0; i < 8; ++i) r[i] = f2bf(a[i] * inv);
        *(ushort8v*)(agg + ((size_t)(t * NN + node)) * 256 + sub * 8) = r;
    }
}

// ---------- copy x into out[:, 0:256] ----------
__global__ void xcopy_k(const float* __restrict__ x, float* __restrict__ out) {
    int i = blockIdx.x * blockDim.x + threadIdx.x;
    if (i < NN * 64) {
        int n = i >> 6;
        int c = i & 63;
        float4 v = ((const float4*)x)[i];
        *(float4*)(out + (size_t)n * 768 + c * 4) = v;
    }
}

extern "C" void kernel_launch(void* const* d_in, const int* in_sizes, int n_in,
                              void* d_out, int out_size, void* d_ws, size_t ws_size,
                              hipStream_t stream)
{
    const float* x      = (const float*)d_in[0];
    const float* W_qkv  = (const float*)d_in[1];
    const float* b_qkv  = (const float*)d_in[2];
    const float* W_out  = (const float*)d_in[3];
    const float* b_out  = (const float*)d_in[4];
    const int* edge_src = (const int*)d_in[5];
    const int* edge_dst = (const int*)d_in[6];
    float* out = (float*)d_out;

    char* ws = (char*)d_ws;
    size_t off = 0;
    auto carve = [&](size_t bytes) {
        char* p = ws + off;
        off += (bytes + 255) & ~(size_t)255;
        return p;
    };
    ushort* xb    = (ushort*)carve((size_t)NN * DIM * 2);
    ushort* wqkvt = (ushort*)carve((size_t)1536 * 256 * 2);
    ushort* woutt = (ushort*)carve((size_t)TT * 256 * 256 * 2);
    ushort* q_ws  = (ushort*)carve((size_t)TT * NN * 256 * 2);
    unsigned char* kv_ws = (unsigned char*)carve((size_t)TT * NN * 512);
    ushort* aggb  = (ushort*)carve((size_t)TT * NN * 256 * 2);
    int* cnt    = (int*)carve((size_t)TT * NN * 4);
    int* offs   = (int*)carve((size_t)TT * (NN + 1) * 4);
    int* cursor = (int*)carve((size_t)TT * NN * 4);
    int* srt    = (int*)carve((size_t)TT * EE * 4);
    int* bsum   = (int*)carve((size_t)TT * NCHUNK * 4);

    (void)hipMemsetAsync(cnt, 0, (size_t)TT * NN * 4, stream);

    cvt_x_k<<<(NN * DIM / 4 + 255) / 256, 256, 0, stream>>>(x, xb, NN * DIM / 4);
    cvt_wt_k<<<(256 * 1536 + 255) / 256, 256, 0, stream>>>(W_qkv, wqkvt, 1536);
    for (int t = 0; t < TT; ++t)
        cvt_wt_k<<<(256 * 256 + 255) / 256, 256, 0, stream>>>(W_out + (size_t)t * 65536,
                                                              woutt + (size_t)t * 65536, 256);

    gemm3_k<0><<<dim3(391, 12), 256, 0, stream>>>(xb, wqkvt, b_qkv, q_ws, kv_ws,
                                                  nullptr, NN, 0);

    count_k<<<(TT * EE / 8 + 255) / 256, 256, 0, stream>>>(edge_dst, cnt);
    partial_k<<<TT * NCHUNK, 256, 0, stream>>>(cnt, bsum);
    scanb_k<<<1, 256, 0, stream>>>(bsum);
    expand_k<<<TT * NCHUNK, 256, 0, stream>>>(cnt, bsum, offs, cursor);
    scatter_k<<<(TT * EE / 8 + 255) / 256, 256, 0, stream>>>(edge_dst, edge_src, cursor, srt);

    attn_k<<<(NN * TT) / 4, 256, 0, stream>>>(q_ws, kv_ws, offs, srt, aggb);

    for (int t = 0; t < TT; ++t)
        gemm3_k<1><<<dim3(391, 2), 256, 0, stream>>>(aggb + (size_t)t * NN * 256,
                                                     woutt + (size_t)t * 65536,
                                                     b_out + (size_t)t * 256,
                                                     nullptr, nullptr,
                                                     out, NN, 256 + t * 256);

    xcopy_k<<<(NN * 64 + 255) / 256, 256, 0, stream>>>(x, out);
}

// Round 9
// 378.441 us; speedup vs baseline: 1.6794x; 1.3555x over previous
//
#include <hip/hip_runtime.h>

#define NN 50000
#define DIM 256
#define HH 8
#define TT 2
#define EE 800000
#define HDIM 32

#define NPART 98        // buckets per t, 512 nodes each
#define RNODE 512
#define BCAP 12288      // bucket capacity (mean 8192, +45 sigma)
#define K1CH 8192       // edges per edge_bucket_k block
#define K1BLK 98        // ceil(EE / K1CH)

typedef __attribute__((ext_vector_type(8))) short short8;
typedef __attribute__((ext_vector_type(8))) unsigned short ushort8v;
typedef __attribute__((ext_vector_type(4))) float f32x4;
typedef __attribute__((ext_vector_type(2))) float f32x2;
typedef __attribute__((ext_vector_type(4))) unsigned int u32x4;

typedef __attribute__((address_space(3))) unsigned int u32_lds;
typedef __attribute__((address_space(1))) const unsigned int u32_glb;

__device__ __forceinline__ float bf2f(ushort u) {
    return __uint_as_float(((unsigned)u) << 16);
}
__device__ __forceinline__ ushort f2bf(float f) {
    unsigned u = __float_as_uint(f);
    unsigned r = u + 0x7fffu + ((u >> 16) & 1u);
    return (ushort)(r >> 16);
}

// fp8 e4m3 packed decode (HW): bytes [0:1] (HI=false) or [2:3] (HI=true) of w
template <bool HI>
__device__ __forceinline__ f32x2 cvtpk8(unsigned w) {
    return __builtin_amdgcn_cvt_pk_f32_fp8((int)w, HI);
}

// ---------- converts ----------
__global__ void cvt_x_k(const float* __restrict__ x, ushort* __restrict__ xb, int n4) {
    int i = blockIdx.x * blockDim.x + threadIdx.x;
    if (i < n4) {
        float4 v = ((const float4*)x)[i];
        ushort4 o;
        o.x = f2bf(v.x); o.y = f2bf(v.y); o.z = f2bf(v.z); o.w = f2bf(v.w);
        ((ushort4*)xb)[i] = o;
    }
}

// W (256 x Ncols) row-major -> Wt (Ncols x 256) bf16
__global__ void cvt_wt_k(const float* __restrict__ W, ushort* __restrict__ Wt, int Ncols) {
    int idx = blockIdx.x * blockDim.x + threadIdx.x;
    int total = 256 * Ncols;
    if (idx < total) {
        int k = idx / Ncols;
        int nn = idx - k * Ncols;
        Wt[nn * 256 + k] = f2bf(W[idx]);
    }
}

// ---------- m97-style MFMA GEMM: 128x128 tile, BK=64, global_load_lds + XOR swizzle ----
template <int EPI>
__global__ __launch_bounds__(256) void gemm3_k(
    const ushort* __restrict__ A, const ushort* __restrict__ Bt,
    const float* __restrict__ bias,
    ushort* __restrict__ qo, unsigned char* __restrict__ kvo,
    float* __restrict__ outf, int M, int col_base)
{
    __shared__ ushort As[128 * 64];
    __shared__ ushort Bs[128 * 64];
    const int tid = threadIdx.x;
    const int lane = tid & 63;
    const int w = tid >> 6;          // 4 waves: 2M x 2N
    const int wr = w >> 1, wc = w & 1;
    const int lr = lane & 15;
    const int lq = lane >> 4;
    const int m0 = blockIdx.x * 128;
    const int n0 = blockIdx.y * 128;

    f32x4 acc[4][4];
#pragma unroll
    for (int mt = 0; mt < 4; ++mt)
#pragma unroll
        for (int nt = 0; nt < 4; ++nt) acc[mt][nt] = (f32x4){0.f, 0.f, 0.f, 0.f};

    for (int ks = 0; ks < 256; ks += 64) {
#pragma unroll
        for (int it = 0; it < 4; ++it) {
            int u = tid + it * 256;          // 0..1023: row=u>>3, slot=u&7
            int r = u >> 3, s = u & 7;
            int ss = (s ^ (r & 7)) << 3;     // pre-swizzled source slot (elements)
            const ushort* srcA = A + (size_t)(m0 + r) * 256 + ks + ss;
            __builtin_amdgcn_global_load_lds((u32_glb*)srcA,
                (u32_lds*)((char*)As + (u << 4)), 16, 0, 0);
            const ushort* srcB = Bt + (size_t)(n0 + r) * 256 + ks + ss;
            __builtin_amdgcn_global_load_lds((u32_glb*)srcB,
                (u32_lds*)((char*)Bs + (u << 4)), 16, 0, 0);
        }
        __syncthreads();

#pragma unroll
        for (int ku = 0; ku < 2; ++ku) {
            short8 a[4], b[4];
#pragma unroll
            for (int mt = 0; mt < 4; ++mt) {
                int row = wr * 64 + mt * 16 + lr;
                int s = ku * 4 + lq;
                a[mt] = *(const short8*)((const char*)As + row * 128 + (((s ^ (row & 7)) & 7) << 4));
            }
#pragma unroll
            for (int nt = 0; nt < 4; ++nt) {
                int row = wc * 64 + nt * 16 + lr;
                int s = ku * 4 + lq;
                b[nt] = *(const short8*)((const char*)Bs + row * 128 + (((s ^ (row & 7)) & 7) << 4));
            }
#pragma unroll
            for (int mt = 0; mt < 4; ++mt)
#pragma unroll
                for (int nt = 0; nt < 4; ++nt)
                    acc[mt][nt] = __builtin_amdgcn_mfma_f32_16x16x32_bf16(a[mt], b[nt], acc[mt][nt], 0, 0, 0);
        }
        __syncthreads();
    }

#pragma unroll
    for (int mt = 0; mt < 4; ++mt) {
        int rowb = m0 + wr * 64 + mt * 16 + (lq << 2);
#pragma unroll
        for (int nt = 0; nt < 4; ++nt) {
            int col = n0 + wc * 64 + nt * 16 + lr;
            float bv = bias[col];
#pragma unroll
            for (int r2 = 0; r2 < 4; ++r2) {
                int rr = rowb + r2;
                if (rr < M) {
                    float val = acc[mt][nt][r2] + bv;
                    if (EPI == 0) {
                        int t = col / 768;
                        int rem = col - t * 768;
                        int h = rem / 96;
                        int rem2 = rem - h * 96;
                        int s3 = rem2 >> 5;
                        int hd = rem2 & 31;
                        int d = h * 32 + hd;
                        if (s3 == 0) {
                            qo[((size_t)(t * NN + rr)) * 256 + d] = f2bf(val);
                        } else {
                            unsigned by = ((unsigned)__builtin_amdgcn_cvt_pk_fp8_f32(val, val, 0, false)) & 0xffu;
                            size_t off = ((size_t)(t * NN + rr)) * 512 +
                                         ((size_t)(d >> 3) << 4) + (d & 7) + ((s3 == 2) ? 8 : 0);
                            kvo[off] = (unsigned char)by;
                        }
                    } else {
                        outf[(size_t)rr * 768 + col_base + col] = val;
                    }
                }
            }
        }
    }
}

// ---------- bucket-partition CSR build (no device atomics on hot path) ----------
// K1: chunk-blocks histogram 98 buckets in LDS, reserve segments with one global
// atomic per bucket, write (src,dst) pairs into exclusive contiguous segments.
__global__ __launch_bounds__(256) void edge_bucket_k(
    const int* __restrict__ dst, const int* __restrict__ src,
    int* __restrict__ bcursor, uint2* __restrict__ bpair)
{
    int t = blockIdx.x / K1BLK;
    int cb = blockIdx.x - t * K1BLK;
    int base = cb * K1CH;
    const int* dp = dst + (size_t)t * EE;
    const int* sp = src + (size_t)t * EE;
    __shared__ int bcnt[NPART];
    __shared__ int bbase_l[NPART];
    int tid = threadIdx.x;
    if (tid < NPART) bcnt[tid] = 0;
    __syncthreads();
    int lim = EE - base; if (lim > K1CH) lim = K1CH;
#pragma unroll 4
    for (int it = 0; it < K1CH / 256; ++it) {
        int i = it * 256 + tid;
        if (i < lim) atomicAdd(&bcnt[dp[base + i] >> 9], 1);
    }
    __syncthreads();
    if (tid < NPART)
        bbase_l[tid] = atomicAdd(&bcursor[t * NPART + tid], bcnt[tid]);
    __syncthreads();
    if (tid < NPART) bcnt[tid] = 0;   // reuse as local cursor
    __syncthreads();
#pragma unroll 4
    for (int it = 0; it < K1CH / 256; ++it) {
        int i = it * 256 + tid;
        if (i < lim) {
            int d = dp[base + i];
            int s = sp[base + i];
            int p = d >> 9;
            int pos = bbase_l[p] + atomicAdd(&bcnt[p], 1);
            if (pos < BCAP)
                bpair[(size_t)(t * NPART + p) * BCAP + pos] = make_uint2((unsigned)s, (unsigned)d);
        }
    }
}

// K2: exclusive scan of 98 bucket counts per t -> global srt base per bucket
__global__ __launch_bounds__(128) void bucket_scan_k(
    const int* __restrict__ bcursor, int* __restrict__ bbase)
{
    __shared__ int sh[TT][128];
    int tid = threadIdx.x;
    for (int t = 0; t < TT; ++t)
        sh[t][tid] = (tid < NPART) ? bcursor[t * NPART + tid] : 0;
    __syncthreads();
    for (int off = 1; off < 128; off <<= 1) {
        int v0 = (tid >= off) ? sh[0][tid - off] : 0;
        int v1 = (tid >= off) ? sh[1][tid - off] : 0;
        __syncthreads();
        sh[0][tid] += v0;
        sh[1][tid] += v1;
        __syncthreads();
    }
    for (int t = 0; t < TT; ++t)
        if (tid < NPART) bbase[t * NPART + tid] = (tid == 0) ? 0 : sh[t][tid - 1];
}

// K3: per bucket: LDS histogram(512) -> scan -> offs (coalesced), LDS-staged
// placement -> coalesced srt segment write.
__global__ __launch_bounds__(512) void bucket_scatter_k(
    const uint2* __restrict__ bpair, const int* __restrict__ bcursor,
    const int* __restrict__ bbase, int* __restrict__ offs, int* __restrict__ srt)
{
    int b = blockIdx.x;              // 0..TT*NPART-1
    int t = b / NPART, p = b - t * NPART;
    int lo = p * RNODE;
    int n = bcursor[b]; if (n > BCAP) n = BCAP;
    int gbase = bbase[b];
    const uint2* ep = bpair + (size_t)b * BCAP;
    __shared__ int hist[RNODE];
    __shared__ int scn[RNODE];
    __shared__ int stage[BCAP];
    int tid = threadIdx.x;
    hist[tid] = 0;
    __syncthreads();
    for (int i = tid; i < n; i += 512)
        atomicAdd(&hist[(int)ep[i].y - lo], 1);
    __syncthreads();
    scn[tid] = hist[tid];
    __syncthreads();
    for (int off = 1; off < RNODE; off <<= 1) {
        int v = (tid >= off) ? scn[tid - off] : 0;
        __syncthreads();
        scn[tid] += v;
        __syncthreads();
    }
    int ex = scn[tid] - hist[tid];
    int node = lo + tid;
    if (node < NN) offs[t * (NN + 1) + node] = gbase + ex;
    if (p == NPART - 1 && tid == 0) offs[t * (NN + 1) + NN] = EE;
    hist[tid] = ex;                  // reuse as per-node cursor
    __syncthreads();
    for (int i = tid; i < n; i += 512) {
        uint2 e = ep[i];
        int pos = atomicAdd(&hist[(int)e.y - lo], 1);
        stage[pos] = (int)e.x;
    }
    __syncthreads();
    int* so = srt + (size_t)t * EE + gbase;
    for (int i = tid; i < n; i += 512) so[i] = stage[i];
}

// ---------- fused edge attention ----------
__device__ __forceinline__ float f8dot(u32x4 kv, const float* q)
{
    f32x2 c0 = cvtpk8<false>(kv[0]);
    f32x2 c1 = cvtpk8<true>(kv[0]);
    f32x2 c2 = cvtpk8<false>(kv[1]);
    f32x2 c3 = cvtpk8<true>(kv[1]);
    return q[0] * c0[0] + q[1] * c0[1] + q[2] * c1[0] + q[3] * c1[1] +
           q[4] * c2[0] + q[5] * c2[1] + q[6] * c3[0] + q[7] * c3[1];
}

__device__ __forceinline__ void f8acc(float p, u32x4 kv, float* a)
{
    f32x2 c0 = cvtpk8<false>(kv[2]);
    f32x2 c1 = cvtpk8<true>(kv[2]);
    f32x2 c2 = cvtpk8<false>(kv[3]);
    f32x2 c3 = cvtpk8<true>(kv[3]);
    a[0] += p * c0[0]; a[1] += p * c0[1];
    a[2] += p * c1[0]; a[3] += p * c1[1];
    a[4] += p * c2[0]; a[5] += p * c2[1];
    a[6] += p * c3[0]; a[7] += p * c3[1];
}

__global__ __launch_bounds__(256) void attn_k(
    const ushort* __restrict__ q_ws, const unsigned char* __restrict__ kv_ws,
    const int* __restrict__ offs, const int* __restrict__ srt,
    ushort* __restrict__ agg)
{
    int wid = blockIdx.x * 4 + (threadIdx.x >> 6);
    int lane = threadIdx.x & 63;
    int half = lane >> 5;
    int sub = lane & 31;
    int t = wid / NN;
    int node = wid - t * NN;

    const ushort* qp = q_ws + ((size_t)(t * NN + node)) * 256 + sub * 8;
    ushort8v qu = *(const ushort8v*)qp;
    float q[8];
#pragma unroll
    for (int i = 0; i < 8; ++i) q[i] = bf2f(qu[i]);

    int o0 = offs[t * (NN + 1) + node];
    int o1 = offs[t * (NN + 1) + node + 1];
    const int* sp = srt + (size_t)t * EE;
    const unsigned char* kvb = kv_ws + (size_t)t * NN * 512 + sub * 16;

    const float scale = 0.17677669529663689f;
    float zA = 0.f, zB = 0.f;
    float aA[8] = {0.f, 0.f, 0.f, 0.f, 0.f, 0.f, 0.f, 0.f};
    float aB[8] = {0.f, 0.f, 0.f, 0.f, 0.f, 0.f, 0.f, 0.f};

    int j = o0;
    for (; j + 4 <= o1; j += 4) {
        int s0 = sp[j + half];
        int s1 = sp[j + 2 + half];
        u32x4 kv0 = *(const u32x4*)(kvb + (size_t)s0 * 512);
        u32x4 kv1 = *(const u32x4*)(kvb + (size_t)s1 * 512);
        float d0 = f8dot(kv0, q);
        float d1 = f8dot(kv1, q);
        d0 += __shfl_xor(d0, 1); d1 += __shfl_xor(d1, 1);
        d0 += __shfl_xor(d0, 2); d1 += __shfl_xor(d1, 2);
        float p0 = __expf(d0 * scale);
        float p1 = __expf(d1 * scale);
        zA += p0; zB += p1;
        f8acc(p0, kv0, aA);
        f8acc(p1, kv1, aB);
    }
    for (; j < o1; j += 2) {
        int e = j + half;
        int valid = (e < o1) ? 1 : 0;
        int s0 = sp[valid ? e : j];
        u32x4 kv0 = *(const u32x4*)(kvb + (size_t)s0 * 512);
        float d0 = f8dot(kv0, q);
        d0 += __shfl_xor(d0, 1);
        d0 += __shfl_xor(d0, 2);
        float p0 = valid ? __expf(d0 * scale) : 0.f;
        zA += p0;
        f8acc(p0, kv0, aA);
    }

    float z = zA + zB;
    z += __shfl_xor(z, 32);
    float a[8];
#pragma unroll
    for (int i = 0; i < 8; ++i) {
        a[i] = aA[i] + aB[i];
        a[i] += __shfl_xor(a[i], 32);
    }

    if (half == 0) {
        float inv = (z > 0.f) ? 1.0f / z : 0.f;
        ushort8v r;
#pragma unroll
        for (int i = 0; i < 8; ++i) r[i] = f2bf(a[i] * inv);
        *(ushort8v*)(agg + ((size_t)(t * NN + node)) * 256 + sub * 8) = r;
    }
}

// ---------- copy x into out[:, 0:256] ----------
__global__ void xcopy_k(const float* __restrict__ x, float* __restrict__ out) {
    int i = blockIdx.x * blockDim.x + threadIdx.x;
    if (i < NN * 64) {
        int n = i >> 6;
        int c = i & 63;
        float4 v = ((const float4*)x)[i];
        *(float4*)(out + (size_t)n * 768 + c * 4) = v;
    }
}

extern "C" void kernel_launch(void* const* d_in, const int* in_sizes, int n_in,
                              void* d_out, int out_size, void* d_ws, size_t ws_size,
                              hipStream_t stream)
{
    const float* x      = (const float*)d_in[0];
    const float* W_qkv  = (const float*)d_in[1];
    const float* b_qkv  = (const float*)d_in[2];
    const float* W_out  = (const float*)d_in[3];
    const float* b_out  = (const float*)d_in[4];
    const int* edge_src = (const int*)d_in[5];
    const int* edge_dst = (const int*)d_in[6];
    float* out = (float*)d_out;

    char* ws = (char*)d_ws;
    size_t off = 0;
    auto carve = [&](size_t bytes) {
        char* p = ws + off;
        off += (bytes + 255) & ~(size_t)255;
        return p;
    };
    ushort* xb    = (ushort*)carve((size_t)NN * DIM * 2);
    ushort* wqkvt = (ushort*)carve((size_t)1536 * 256 * 2);
    ushort* woutt = (ushort*)carve((size_t)TT * 256 * 256 * 2);
    ushort* q_ws  = (ushort*)carve((size_t)TT * NN * 256 * 2);
    unsigned char* kv_ws = (unsigned char*)carve((size_t)TT * NN * 512);
    ushort* aggb  = (ushort*)carve((size_t)TT * NN * 256 * 2);
    int* offs     = (int*)carve((size_t)TT * (NN + 1) * 4);
    int* srt      = (int*)carve((size_t)TT * EE * 4);
    uint2* bpair  = (uint2*)carve((size_t)TT * NPART * BCAP * 8);
    int* bcursor  = (int*)carve((size_t)TT * NPART * 4);
    int* bbase    = (int*)carve((size_t)TT * NPART * 4);

    (void)hipMemsetAsync(bcursor, 0, (size_t)TT * NPART * 4, stream);

    cvt_x_k<<<(NN * DIM / 4 + 255) / 256, 256, 0, stream>>>(x, xb, NN * DIM / 4);
    cvt_wt_k<<<(256 * 1536 + 255) / 256, 256, 0, stream>>>(W_qkv, wqkvt, 1536);
    for (int t = 0; t < TT; ++t)
        cvt_wt_k<<<(256 * 256 + 255) / 256, 256, 0, stream>>>(W_out + (size_t)t * 65536,
                                                              woutt + (size_t)t * 65536, 256);

    gemm3_k<0><<<dim3(391, 12), 256, 0, stream>>>(xb, wqkvt, b_qkv, q_ws, kv_ws,
                                                  nullptr, NN, 0);

    edge_bucket_k<<<TT * K1BLK, 256, 0, stream>>>(edge_dst, edge_src, bcursor, bpair);
    bucket_scan_k<<<1, 128, 0, stream>>>(bcursor, bbase);
    bucket_scatter_k<<<TT * NPART, 512, 0, stream>>>(bpair, bcursor, bbase, offs, srt);

    attn_k<<<(NN * TT) / 4, 256, 0, stream>>>(q_ws, kv_ws, offs, srt, aggb);

    for (int t = 0; t < TT; ++t)
        gemm3_k<1><<<dim3(391, 2), 256, 0, stream>>>(aggb + (size_t)t * NN * 256,
                                                     woutt + (size_t)t * 65536,
                                                     b_out + (size_t)t * 256,
                                                     nullptr, nullptr,
                                                     out, NN, 256 + t * 256);

    xcopy_k<<<(NN * 64 + 255) / 256, 256, 0, stream>>>(x, out);
}

// Round 10
// 368.326 us; speedup vs baseline: 1.7255x; 1.0275x over previous
//
#include <hip/hip_runtime.h>

#define NN 50000
#define DIM 256
#define HH 8
#define TT 2
#define EE 800000
#define HDIM 32

#define NPART 98        // buckets per t, 512 nodes each
#define RNODE 512
#define BCAP 12288      // bucket capacity (mean 8192, +45 sigma)
#define K1CH 8192       // edges per edge_bucket_k block
#define K1BLK 98        // ceil(EE / K1CH)

typedef __attribute__((ext_vector_type(8))) short short8;
typedef __attribute__((ext_vector_type(8))) unsigned short ushort8v;
typedef __attribute__((ext_vector_type(4))) float f32x4;
typedef __attribute__((ext_vector_type(2))) float f32x2;
typedef __attribute__((ext_vector_type(4))) unsigned int u32x4;

typedef __attribute__((address_space(3))) unsigned int u32_lds;
typedef __attribute__((address_space(1))) const unsigned int u32_glb;

__device__ __forceinline__ float bf2f(ushort u) {
    return __uint_as_float(((unsigned)u) << 16);
}
__device__ __forceinline__ ushort f2bf(float f) {
    unsigned u = __float_as_uint(f);
    unsigned r = u + 0x7fffu + ((u >> 16) & 1u);
    return (ushort)(r >> 16);
}

// fp8 e4m3 packed decode (HW): bytes [0:1] (HI=false) or [2:3] (HI=true) of w
template <bool HI>
__device__ __forceinline__ f32x2 cvtpk8(unsigned w) {
    return __builtin_amdgcn_cvt_pk_f32_fp8((int)w, HI);
}

// ---------- fused convert: x -> bf16 xb AND out[:, 0:256] ----------
__global__ void cvt_xout_k(const float* __restrict__ x, ushort* __restrict__ xb,
                           float* __restrict__ out) {
    int i = blockIdx.x * blockDim.x + threadIdx.x;
    if (i < NN * 64) {
        int n = i >> 6;
        int c = i & 63;
        float4 v = ((const float4*)x)[i];
        ushort4 o;
        o.x = f2bf(v.x); o.y = f2bf(v.y); o.z = f2bf(v.z); o.w = f2bf(v.w);
        ((ushort4*)xb)[i] = o;
        *(float4*)(out + (size_t)n * 768 + c * 4) = v;
    }
}

// all weights transposed/converted in one launch:
// idx < 393216: W_qkv (256 x 1536) -> wqkvt (1536 x 256)
// else: W_out (2 x 256 x 256) -> woutt (2 x 256 x 256 transposed)
__global__ void cvt_w_k(const float* __restrict__ Wqkv, const float* __restrict__ Wout,
                        ushort* __restrict__ wqkvt, ushort* __restrict__ woutt) {
    int idx = blockIdx.x * blockDim.x + threadIdx.x;
    if (idx < 256 * 1536) {
        int k = idx / 1536;
        int nn = idx - k * 1536;
        wqkvt[nn * 256 + k] = f2bf(Wqkv[idx]);
    } else {
        int j = idx - 256 * 1536;
        if (j < TT * 65536) {
            int t = j >> 16;
            int r = j & 65535;
            int k = r >> 8;
            int nn = r & 255;
            woutt[t * 65536 + nn * 256 + k] = f2bf(Wout[t * 65536 + k * 256 + nn]);
        }
    }
}

// ---------- m97-style MFMA GEMM: 128x128 tile, BK=64, global_load_lds + XOR swizzle ----
// EPI 0: grid (391, 12), C = xb @ wqkvt^T; epilogue scatters q bf16 / kv fp8.
// EPI 1: grid (391, 4): t = y>>1, n0 = (y&1)*128; C = aggb[t] @ woutt[t]^T -> out.
template <int EPI>
__global__ __launch_bounds__(256) void gemm3_k(
    const ushort* __restrict__ A, const ushort* __restrict__ Bt,
    const float* __restrict__ bias,
    ushort* __restrict__ qo, unsigned char* __restrict__ kvo,
    float* __restrict__ outf, int M)
{
    __shared__ ushort As[128 * 64];
    __shared__ ushort Bs[128 * 64];
    const int tid = threadIdx.x;
    const int lane = tid & 63;
    const int w = tid >> 6;          // 4 waves: 2M x 2N
    const int wr = w >> 1, wc = w & 1;
    const int lr = lane & 15;
    const int lq = lane >> 4;
    const int m0 = blockIdx.x * 128;

    int n0, col_base = 0, tsel = 0;
    if (EPI == 0) {
        n0 = blockIdx.y * 128;
    } else {
        tsel = blockIdx.y >> 1;
        n0 = (blockIdx.y & 1) * 128;
        col_base = 256 + tsel * 256;
    }
    const ushort* A_  = (EPI == 0) ? A  : A  + (size_t)tsel * NN * 256;
    const ushort* Bt_ = (EPI == 0) ? Bt : Bt + (size_t)tsel * 65536;
    const float* bias_ = (EPI == 0) ? bias : bias + tsel * 256;

    f32x4 acc[4][4];
#pragma unroll
    for (int mt = 0; mt < 4; ++mt)
#pragma unroll
        for (int nt = 0; nt < 4; ++nt) acc[mt][nt] = (f32x4){0.f, 0.f, 0.f, 0.f};

    for (int ks = 0; ks < 256; ks += 64) {
#pragma unroll
        for (int it = 0; it < 4; ++it) {
            int u = tid + it * 256;          // 0..1023: row=u>>3, slot=u&7
            int r = u >> 3, s = u & 7;
            int ss = (s ^ (r & 7)) << 3;     // pre-swizzled source slot (elements)
            const ushort* srcA = A_ + (size_t)(m0 + r) * 256 + ks + ss;
            __builtin_amdgcn_global_load_lds((u32_glb*)srcA,
                (u32_lds*)((char*)As + (u << 4)), 16, 0, 0);
            const ushort* srcB = Bt_ + (size_t)(n0 + r) * 256 + ks + ss;
            __builtin_amdgcn_global_load_lds((u32_glb*)srcB,
                (u32_lds*)((char*)Bs + (u << 4)), 16, 0, 0);
        }
        __syncthreads();

#pragma unroll
        for (int ku = 0; ku < 2; ++ku) {
            short8 a[4], b[4];
#pragma unroll
            for (int mt = 0; mt < 4; ++mt) {
                int row = wr * 64 + mt * 16 + lr;
                int s = ku * 4 + lq;
                a[mt] = *(const short8*)((const char*)As + row * 128 + (((s ^ (row & 7)) & 7) << 4));
            }
#pragma unroll
            for (int nt = 0; nt < 4; ++nt) {
                int row = wc * 64 + nt * 16 + lr;
                int s = ku * 4 + lq;
                b[nt] = *(const short8*)((const char*)Bs + row * 128 + (((s ^ (row & 7)) & 7) << 4));
            }
#pragma unroll
            for (int mt = 0; mt < 4; ++mt)
#pragma unroll
                for (int nt = 0; nt < 4; ++nt)
                    acc[mt][nt] = __builtin_amdgcn_mfma_f32_16x16x32_bf16(a[mt], b[nt], acc[mt][nt], 0, 0, 0);
        }
        __syncthreads();
    }

#pragma unroll
    for (int mt = 0; mt < 4; ++mt) {
        int rowb = m0 + wr * 64 + mt * 16 + (lq << 2);
#pragma unroll
        for (int nt = 0; nt < 4; ++nt) {
            int col = n0 + wc * 64 + nt * 16 + lr;
            float bv = bias_[col];
#pragma unroll
            for (int r2 = 0; r2 < 4; ++r2) {
                int rr = rowb + r2;
                if (rr < M) {
                    float val = acc[mt][nt][r2] + bv;
                    if (EPI == 0) {
                        int t = col / 768;
                        int rem = col - t * 768;
                        int h = rem / 96;
                        int rem2 = rem - h * 96;
                        int s3 = rem2 >> 5;
                        int hd = rem2 & 31;
                        int d = h * 32 + hd;
                        if (s3 == 0) {
                            qo[((size_t)(t * NN + rr)) * 256 + d] = f2bf(val);
                        } else {
                            unsigned by = ((unsigned)__builtin_amdgcn_cvt_pk_fp8_f32(val, val, 0, false)) & 0xffu;
                            size_t off = ((size_t)(t * NN + rr)) * 512 +
                                         ((size_t)(d >> 3) << 4) + (d & 7) + ((s3 == 2) ? 8 : 0);
                            kvo[off] = (unsigned char)by;
                        }
                    } else {
                        outf[(size_t)rr * 768 + col_base + col] = val;
                    }
                }
            }
        }
    }
}

// ---------- bucket-partition CSR build ----------
__global__ __launch_bounds__(256) void edge_bucket_k(
    const int* __restrict__ dst, const int* __restrict__ src,
    int* __restrict__ bcursor, uint2* __restrict__ bpair)
{
    int t = blockIdx.x / K1BLK;
    int cb = blockIdx.x - t * K1BLK;
    int base = cb * K1CH;
    const int* dp = dst + (size_t)t * EE;
    const int* sp = src + (size_t)t * EE;
    __shared__ int bcnt[NPART];
    __shared__ int bbase_l[NPART];
    int tid = threadIdx.x;
    if (tid < NPART) bcnt[tid] = 0;
    __syncthreads();
    int lim = EE - base; if (lim > K1CH) lim = K1CH;
#pragma unroll 4
    for (int it = 0; it < K1CH / 256; ++it) {
        int i = it * 256 + tid;
        if (i < lim) atomicAdd(&bcnt[dp[base + i] >> 9], 1);
    }
    __syncthreads();
    if (tid < NPART)
        bbase_l[tid] = atomicAdd(&bcursor[t * NPART + tid], bcnt[tid]);
    __syncthreads();
    if (tid < NPART) bcnt[tid] = 0;   // reuse as local cursor
    __syncthreads();
#pragma unroll 4
    for (int it = 0; it < K1CH / 256; ++it) {
        int i = it * 256 + tid;
        if (i < lim) {
            int d = dp[base + i];
            int s = sp[base + i];
            int p = d >> 9;
            int pos = bbase_l[p] + atomicAdd(&bcnt[p], 1);
            if (pos < BCAP)
                bpair[(size_t)(t * NPART + p) * BCAP + pos] = make_uint2((unsigned)s, (unsigned)d);
        }
    }
}

__global__ __launch_bounds__(128) void bucket_scan_k(
    const int* __restrict__ bcursor, int* __restrict__ bbase)
{
    __shared__ int sh[TT][128];
    int tid = threadIdx.x;
    for (int t = 0; t < TT; ++t)
        sh[t][tid] = (tid < NPART) ? bcursor[t * NPART + tid] : 0;
    __syncthreads();
    for (int off = 1; off < 128; off <<= 1) {
        int v0 = (tid >= off) ? sh[0][tid - off] : 0;
        int v1 = (tid >= off) ? sh[1][tid - off] : 0;
        __syncthreads();
        sh[0][tid] += v0;
        sh[1][tid] += v1;
        __syncthreads();
    }
    for (int t = 0; t < TT; ++t)
        if (tid < NPART) bbase[t * NPART + tid] = (tid == 0) ? 0 : sh[t][tid - 1];
}

__global__ __launch_bounds__(512) void bucket_scatter_k(
    const uint2* __restrict__ bpair, const int* __restrict__ bcursor,
    const int* __restrict__ bbase, int* __restrict__ offs, int* __restrict__ srt)
{
    int b = blockIdx.x;              // 0..TT*NPART-1
    int t = b / NPART, p = b - t * NPART;
    int lo = p * RNODE;
    int n = bcursor[b]; if (n > BCAP) n = BCAP;
    int gbase = bbase[b];
    const uint2* ep = bpair + (size_t)b * BCAP;
    __shared__ int hist[RNODE];
    __shared__ int scn[RNODE];
    __shared__ int stage[BCAP];
    int tid = threadIdx.x;
    hist[tid] = 0;
    __syncthreads();
    for (int i = tid; i < n; i += 512)
        atomicAdd(&hist[(int)ep[i].y - lo], 1);
    __syncthreads();
    scn[tid] = hist[tid];
    __syncthreads();
    for (int off = 1; off < RNODE; off <<= 1) {
        int v = (tid >= off) ? scn[tid - off] : 0;
        __syncthreads();
        scn[tid] += v;
        __syncthreads();
    }
    int ex = scn[tid] - hist[tid];
    int node = lo + tid;
    if (node < NN) offs[t * (NN + 1) + node] = gbase + ex;
    if (p == NPART - 1 && tid == 0) offs[t * (NN + 1) + NN] = EE;
    hist[tid] = ex;                  // reuse as per-node cursor
    __syncthreads();
    for (int i = tid; i < n; i += 512) {
        uint2 e = ep[i];
        int pos = atomicAdd(&hist[(int)e.y - lo], 1);
        stage[pos] = (int)e.x;
    }
    __syncthreads();
    int* so = srt + (size_t)t * EE + gbase;
    for (int i = tid; i < n; i += 512) so[i] = stage[i];
}

// ---------- fused edge attention (packed f32x2 math, 8-edge unroll) ----------
__device__ __forceinline__ float f8dot2(u32x4 kv, const f32x2* q2)
{
    f32x2 dd = q2[0] * cvtpk8<false>(kv[0]);
    dd += q2[1] * cvtpk8<true>(kv[0]);
    dd += q2[2] * cvtpk8<false>(kv[1]);
    dd += q2[3] * cvtpk8<true>(kv[1]);
    return dd[0] + dd[1];
}

__device__ __forceinline__ void f8acc2(float p, u32x4 kv, f32x2* a2)
{
    f32x2 p2 = {p, p};
    a2[0] += p2 * cvtpk8<false>(kv[2]);
    a2[1] += p2 * cvtpk8<true>(kv[2]);
    a2[2] += p2 * cvtpk8<false>(kv[3]);
    a2[3] += p2 * cvtpk8<true>(kv[3]);
}

__global__ __launch_bounds__(256) void attn_k(
    const ushort* __restrict__ q_ws, const unsigned char* __restrict__ kv_ws,
    const int* __restrict__ offs, const int* __restrict__ srt,
    ushort* __restrict__ agg)
{
    int wid = blockIdx.x * 4 + (threadIdx.x >> 6);
    int lane = threadIdx.x & 63;
    int half = lane >> 5;
    int sub = lane & 31;
    int t = wid / NN;
    int node = wid - t * NN;

    const ushort* qp = q_ws + ((size_t)(t * NN + node)) * 256 + sub * 8;
    ushort8v qu = *(const ushort8v*)qp;
    f32x2 q2[4];
#pragma unroll
    for (int i = 0; i < 4; ++i)
        q2[i] = (f32x2){bf2f(qu[2 * i]), bf2f(qu[2 * i + 1])};

    int o0 = offs[t * (NN + 1) + node];
    int o1 = offs[t * (NN + 1) + node + 1];
    const int* sp = srt + (size_t)t * EE;
    const unsigned char* kvb = kv_ws + (size_t)t * NN * 512 + sub * 16;

    const float scale = 0.17677669529663689f;
    float zA = 0.f, zB = 0.f;
    f32x2 aA[4] = {{0.f,0.f},{0.f,0.f},{0.f,0.f},{0.f,0.f}};
    f32x2 aB[4] = {{0.f,0.f},{0.f,0.f},{0.f,0.f},{0.f,0.f}};

    int j = o0;
    for (; j + 8 <= o1; j += 8) {
        int s0 = sp[j + half];
        int s1 = sp[j + 2 + half];
        int s2 = sp[j + 4 + half];
        int s3 = sp[j + 6 + half];
        u32x4 kv0 = *(const u32x4*)(kvb + (size_t)s0 * 512);
        u32x4 kv1 = *(const u32x4*)(kvb + (size_t)s1 * 512);
        u32x4 kv2 = *(const u32x4*)(kvb + (size_t)s2 * 512);
        u32x4 kv3 = *(const u32x4*)(kvb + (size_t)s3 * 512);
        float d0 = f8dot2(kv0, q2);
        float d1 = f8dot2(kv1, q2);
        float d2 = f8dot2(kv2, q2);
        float d3 = f8dot2(kv3, q2);
        d0 += __shfl_xor(d0, 1); d1 += __shfl_xor(d1, 1);
        d2 += __shfl_xor(d2, 1); d3 += __shfl_xor(d3, 1);
        d0 += __shfl_xor(d0, 2); d1 += __shfl_xor(d1, 2);
        d2 += __shfl_xor(d2, 2); d3 += __shfl_xor(d3, 2);
        float p0 = __expf(d0 * scale);
        float p1 = __expf(d1 * scale);
        float p2 = __expf(d2 * scale);
        float p3 = __expf(d3 * scale);
        zA += p0 + p2; zB += p1 + p3;
        f8acc2(p0, kv0, aA);
        f8acc2(p1, kv1, aB);
        f8acc2(p2, kv2, aA);
        f8acc2(p3, kv3, aB);
    }
    for (; j + 4 <= o1; j += 4) {
        int s0 = sp[j + half];
        int s1 = sp[j + 2 + half];
        u32x4 kv0 = *(const u32x4*)(kvb + (size_t)s0 * 512);
        u32x4 kv1 = *(const u32x4*)(kvb + (size_t)s1 * 512);
        float d0 = f8dot2(kv0, q2);
        float d1 = f8dot2(kv1, q2);
        d0 += __shfl_xor(d0, 1); d1 += __shfl_xor(d1, 1);
        d0 += __shfl_xor(d0, 2); d1 += __shfl_xor(d1, 2);
        float p0 = __expf(d0 * scale);
        float p1 = __expf(d1 * scale);
        zA += p0; zB += p1;
        f8acc2(p0, kv0, aA);
        f8acc2(p1, kv1, aB);
    }
    for (; j < o1; j += 2) {
        int e = j + half;
        int valid = (e < o1) ? 1 : 0;
        int s0 = sp[valid ? e : j];
        u32x4 kv0 = *(const u32x4*)(kvb + (size_t)s0 * 512);
        float d0 = f8dot2(kv0, q2);
        d0 += __shfl_xor(d0, 1);
        d0 += __shfl_xor(d0, 2);
        float p0 = valid ? __expf(d0 * scale) : 0.f;
        zA += p0;
        f8acc2(p0, kv0, aA);
    }

    float z = zA + zB;
    z += __shfl_xor(z, 32);
    float a[8];
#pragma unroll
    for (int i = 0; i < 4; ++i) {
        f32x2 s2 = aA[i] + aB[i];
        a[2 * i]     = s2[0];
        a[2 * i + 1] = s2[1];
    }
#pragma unroll
    for (int i = 0; i < 8; ++i) a[i] += __shfl_xor(a[i], 32);

    if (half == 0) {
        float inv = (z > 0.f) ? 1.0f / z : 0.f;
        ushort8v r;
#pragma unroll
        for (int i = 0; i < 8; ++i) r[i] = f2bf(a[i] * inv);
        *(ushort8v*)(agg + ((size_t)(t * NN + node)) * 256 + sub * 8) = r;
    }
}

extern "C" void kernel_launch(void* const* d_in, const int* in_sizes, int n_in,
                              void* d_out, int out_size, void* d_ws, size_t ws_size,
                              hipStream_t stream)
{
    const float* x      = (const float*)d_in[0];
    const float* W_qkv  = (const float*)d_in[1];
    const float* b_qkv  = (const float*)d_in[2];
    const float* W_out  = (const float*)d_in[3];
    const float* b_out  = (const float*)d_in[4];
    const int* edge_src = (const int*)d_in[5];
    const int* edge_dst = (const int*)d_in[6];
    float* out = (float*)d_out;

    char* ws = (char*)d_ws;
    size_t off = 0;
    auto carve = [&](size_t bytes) {
        char* p = ws + off;
        off += (bytes + 255) & ~(size_t)255;
        return p;
    };
    ushort* xb    = (ushort*)carve((size_t)NN * DIM * 2);
    ushort* wqkvt = (ushort*)carve((size_t)1536 * 256 * 2);
    ushort* woutt = (ushort*)carve((size_t)TT * 256 * 256 * 2);
    ushort* q_ws  = (ushort*)carve((size_t)TT * NN * 256 * 2);
    unsigned char* kv_ws = (unsigned char*)carve((size_t)TT * NN * 512);
    ushort* aggb  = (ushort*)carve((size_t)TT * NN * 256 * 2);
    int* offs     = (int*)carve((size_t)TT * (NN + 1) * 4);
    int* srt      = (int*)carve((size_t)TT * EE * 4);
    uint2* bpair  = (uint2*)carve((size_t)TT * NPART * BCAP * 8);
    int* bcursor  = (int*)carve((size_t)TT * NPART * 4);
    int* bbase    = (int*)carve((size_t)TT * NPART * 4);

    (void)hipMemsetAsync(bcursor, 0, (size_t)TT * NPART * 4, stream);

    cvt_xout_k<<<(NN * 64 + 255) / 256, 256, 0, stream>>>(x, xb, out);
    cvt_w_k<<<(256 * 1536 + TT * 65536 + 255) / 256, 256, 0, stream>>>(W_qkv, W_out,
                                                                       wqkvt, woutt);

    gemm3_k<0><<<dim3(391, 12), 256, 0, stream>>>(xb, wqkvt, b_qkv, q_ws, kv_ws,
                                                  nullptr, NN);

    edge_bucket_k<<<TT * K1BLK, 256, 0, stream>>>(edge_dst, edge_src, bcursor, bpair);
    bucket_scan_k<<<1, 128, 0, stream>>>(bcursor, bbase);
    bucket_scatter_k<<<TT * NPART, 512, 0, stream>>>(bpair, bcursor, bbase, offs, srt);

    attn_k<<<(NN * TT) / 4, 256, 0, stream>>>(q_ws, kv_ws, offs, srt, aggb);

    gemm3_k<1><<<dim3(391, 4), 256, 0, stream>>>(aggb, woutt, b_out,
                                                 nullptr, nullptr, out, NN);
}

// Round 11
// 339.444 us; speedup vs baseline: 1.8723x; 1.0851x over previous
//
#include <hip/hip_runtime.h>

#define NN 50000
#define DIM 256
#define HH 8
#define TT 2
#define EE 800000
#define HDIM 32

#define NPART 98        // buckets per t, 512 nodes each
#define RNODE 512
#define BCAP 12288      // bucket capacity (mean 8192, +45 sigma)
#define K1CH 8192       // edges per edge_bucket_k block
#define K1BLK 98        // ceil(EE / K1CH)

typedef __attribute__((ext_vector_type(8))) short short8;
typedef __attribute__((ext_vector_type(8))) unsigned short ushort8v;
typedef __attribute__((ext_vector_type(4))) float f32x4;
typedef __attribute__((ext_vector_type(2))) float f32x2;
typedef __attribute__((ext_vector_type(4))) unsigned int u32x4;

typedef __attribute__((address_space(3))) unsigned int u32_lds;
typedef __attribute__((address_space(1))) const unsigned int u32_glb;

__device__ __forceinline__ float bf2f(ushort u) {
    return __uint_as_float(((unsigned)u) << 16);
}
__device__ __forceinline__ ushort f2bf(float f) {
    unsigned u = __float_as_uint(f);
    unsigned r = u + 0x7fffu + ((u >> 16) & 1u);
    return (ushort)(r >> 16);
}

// fp8 e4m3 packed decode (HW): bytes [0:1] (HI=false) or [2:3] (HI=true) of w
template <bool HI>
__device__ __forceinline__ f32x2 cvtpk8(unsigned w) {
    return __builtin_amdgcn_cvt_pk_f32_fp8((int)w, HI);
}

// ---------- fused convert: x -> bf16 xb AND out[:, 0:256] ----------
__global__ void cvt_xout_k(const float* __restrict__ x, ushort* __restrict__ xb,
                           float* __restrict__ out) {
    int i = blockIdx.x * blockDim.x + threadIdx.x;
    if (i < NN * 64) {
        int n = i >> 6;
        int c = i & 63;
        float4 v = ((const float4*)x)[i];
        ushort4 o;
        o.x = f2bf(v.x); o.y = f2bf(v.y); o.z = f2bf(v.z); o.w = f2bf(v.w);
        ((ushort4*)xb)[i] = o;
        *(float4*)(out + (size_t)n * 768 + c * 4) = v;
    }
}

// all weights transposed/converted in one launch
__global__ void cvt_w_k(const float* __restrict__ Wqkv, const float* __restrict__ Wout,
                        ushort* __restrict__ wqkvt, ushort* __restrict__ woutt) {
    int idx = blockIdx.x * blockDim.x + threadIdx.x;
    if (idx < 256 * 1536) {
        int k = idx / 1536;
        int nn = idx - k * 1536;
        wqkvt[nn * 256 + k] = f2bf(Wqkv[idx]);
    } else {
        int j = idx - 256 * 1536;
        if (j < TT * 65536) {
            int t = j >> 16;
            int r = j & 65535;
            int k = r >> 8;
            int nn = r & 255;
            woutt[t * 65536 + nn * 256 + k] = f2bf(Wout[t * 65536 + k * 256 + nn]);
        }
    }
}

// ---------- m97-style MFMA GEMM: 128x128 tile, BK=64, global_load_lds + XOR swizzle ----
template <int EPI>
__global__ __launch_bounds__(256) void gemm3_k(
    const ushort* __restrict__ A, const ushort* __restrict__ Bt,
    const float* __restrict__ bias,
    ushort* __restrict__ qo, unsigned char* __restrict__ kvo,
    float* __restrict__ outf, int M)
{
    __shared__ ushort As[128 * 64];
    __shared__ ushort Bs[128 * 64];
    const int tid = threadIdx.x;
    const int lane = tid & 63;
    const int w = tid >> 6;          // 4 waves: 2M x 2N
    const int wr = w >> 1, wc = w & 1;
    const int lr = lane & 15;
    const int lq = lane >> 4;
    const int m0 = blockIdx.x * 128;

    int n0, col_base = 0, tsel = 0;
    if (EPI == 0) {
        n0 = blockIdx.y * 128;
    } else {
        tsel = blockIdx.y >> 1;
        n0 = (blockIdx.y & 1) * 128;
        col_base = 256 + tsel * 256;
    }
    const ushort* A_  = (EPI == 0) ? A  : A  + (size_t)tsel * NN * 256;
    const ushort* Bt_ = (EPI == 0) ? Bt : Bt + (size_t)tsel * 65536;
    const float* bias_ = (EPI == 0) ? bias : bias + tsel * 256;

    f32x4 acc[4][4];
#pragma unroll
    for (int mt = 0; mt < 4; ++mt)
#pragma unroll
        for (int nt = 0; nt < 4; ++nt) acc[mt][nt] = (f32x4){0.f, 0.f, 0.f, 0.f};

    for (int ks = 0; ks < 256; ks += 64) {
#pragma unroll
        for (int it = 0; it < 4; ++it) {
            int u = tid + it * 256;          // 0..1023: row=u>>3, slot=u&7
            int r = u >> 3, s = u & 7;
            int ss = (s ^ (r & 7)) << 3;     // pre-swizzled source slot (elements)
            const ushort* srcA = A_ + (size_t)(m0 + r) * 256 + ks + ss;
            __builtin_amdgcn_global_load_lds((u32_glb*)srcA,
                (u32_lds*)((char*)As + (u << 4)), 16, 0, 0);
            const ushort* srcB = Bt_ + (size_t)(n0 + r) * 256 + ks + ss;
            __builtin_amdgcn_global_load_lds((u32_glb*)srcB,
                (u32_lds*)((char*)Bs + (u << 4)), 16, 0, 0);
        }
        __syncthreads();

#pragma unroll
        for (int ku = 0; ku < 2; ++ku) {
            short8 a[4], b[4];
#pragma unroll
            for (int mt = 0; mt < 4; ++mt) {
                int row = wr * 64 + mt * 16 + lr;
                int s = ku * 4 + lq;
                a[mt] = *(const short8*)((const char*)As + row * 128 + (((s ^ (row & 7)) & 7) << 4));
            }
#pragma unroll
            for (int nt = 0; nt < 4; ++nt) {
                int row = wc * 64 + nt * 16 + lr;
                int s = ku * 4 + lq;
                b[nt] = *(const short8*)((const char*)Bs + row * 128 + (((s ^ (row & 7)) & 7) << 4));
            }
#pragma unroll
            for (int mt = 0; mt < 4; ++mt)
#pragma unroll
                for (int nt = 0; nt < 4; ++nt)
                    acc[mt][nt] = __builtin_amdgcn_mfma_f32_16x16x32_bf16(a[mt], b[nt], acc[mt][nt], 0, 0, 0);
        }
        __syncthreads();
    }

#pragma unroll
    for (int mt = 0; mt < 4; ++mt) {
        int rowb = m0 + wr * 64 + mt * 16 + (lq << 2);
#pragma unroll
        for (int nt = 0; nt < 4; ++nt) {
            int col = n0 + wc * 64 + nt * 16 + lr;
            float bv = bias_[col];
#pragma unroll
            for (int r2 = 0; r2 < 4; ++r2) {
                int rr = rowb + r2;
                if (rr < M) {
                    float val = acc[mt][nt][r2] + bv;
                    if (EPI == 0) {
                        int t = col / 768;
                        int rem = col - t * 768;
                        int h = rem / 96;
                        int rem2 = rem - h * 96;
                        int s3 = rem2 >> 5;
                        int hd = rem2 & 31;
                        int d = h * 32 + hd;
                        if (s3 == 0) {
                            qo[((size_t)(t * NN + rr)) * 256 + d] = f2bf(val);
                        } else {
                            unsigned by = ((unsigned)__builtin_amdgcn_cvt_pk_fp8_f32(val, val, 0, false)) & 0xffu;
                            size_t off = ((size_t)(t * NN + rr)) * 512 +
                                         ((size_t)(d >> 3) << 4) + (d & 7) + ((s3 == 2) ? 8 : 0);
                            kvo[off] = (unsigned char)by;
                        }
                    } else {
                        outf[(size_t)rr * 768 + col_base + col] = val;
                    }
                }
            }
        }
    }
}

// ---------- bucket-partition CSR build ----------
__global__ __launch_bounds__(256) void edge_bucket_k(
    const int* __restrict__ dst, const int* __restrict__ src,
    int* __restrict__ bcursor, uint2* __restrict__ bpair)
{
    int t = blockIdx.x / K1BLK;
    int cb = blockIdx.x - t * K1BLK;
    int base = cb * K1CH;
    const int* dp = dst + (size_t)t * EE;
    const int* sp = src + (size_t)t * EE;
    __shared__ int bcnt[NPART];
    __shared__ int bbase_l[NPART];
    int tid = threadIdx.x;
    if (tid < NPART) bcnt[tid] = 0;
    __syncthreads();
    int lim = EE - base; if (lim > K1CH) lim = K1CH;
    // 4 edges per thread per iter via int4 (K1CH = 8192 = 256 * 4 * 8)
#pragma unroll
    for (int it = 0; it < K1CH / 1024; ++it) {
        int i = (it * 256 + tid) * 4;
        if (i < lim) {
            int4 d4 = *(const int4*)(dp + base + i);
            atomicAdd(&bcnt[d4.x >> 9], 1);
            atomicAdd(&bcnt[d4.y >> 9], 1);
            atomicAdd(&bcnt[d4.z >> 9], 1);
            atomicAdd(&bcnt[d4.w >> 9], 1);
        }
    }
    __syncthreads();
    if (tid < NPART)
        bbase_l[tid] = atomicAdd(&bcursor[t * NPART + tid], bcnt[tid]);
    __syncthreads();
    if (tid < NPART) bcnt[tid] = 0;   // reuse as local cursor
    __syncthreads();
#pragma unroll
    for (int it = 0; it < K1CH / 1024; ++it) {
        int i = (it * 256 + tid) * 4;
        if (i < lim) {
            int4 d4 = *(const int4*)(dp + base + i);
            int4 s4 = *(const int4*)(sp + base + i);
            int dd[4] = {d4.x, d4.y, d4.z, d4.w};
            int ss[4] = {s4.x, s4.y, s4.z, s4.w};
#pragma unroll
            for (int e = 0; e < 4; ++e) {
                int p = dd[e] >> 9;
                int pos = bbase_l[p] + atomicAdd(&bcnt[p], 1);
                if (pos < BCAP)
                    bpair[(size_t)(t * NPART + p) * BCAP + pos] =
                        make_uint2((unsigned)ss[e], (unsigned)dd[e]);
            }
        }
    }
}

__global__ __launch_bounds__(128) void bucket_scan_k(
    const int* __restrict__ bcursor, int* __restrict__ bbase)
{
    __shared__ int sh[TT][128];
    int tid = threadIdx.x;
    for (int t = 0; t < TT; ++t)
        sh[t][tid] = (tid < NPART) ? bcursor[t * NPART + tid] : 0;
    __syncthreads();
    for (int off = 1; off < 128; off <<= 1) {
        int v0 = (tid >= off) ? sh[0][tid - off] : 0;
        int v1 = (tid >= off) ? sh[1][tid - off] : 0;
        __syncthreads();
        sh[0][tid] += v0;
        sh[1][tid] += v1;
        __syncthreads();
    }
    for (int t = 0; t < TT; ++t)
        if (tid < NPART) bbase[t * NPART + tid] = (tid == 0) ? 0 : sh[t][tid - 1];
}

__global__ __launch_bounds__(512) void bucket_scatter_k(
    const uint2* __restrict__ bpair, const int* __restrict__ bcursor,
    const int* __restrict__ bbase, int* __restrict__ offs, int* __restrict__ srt)
{
    int b = blockIdx.x;              // 0..TT*NPART-1
    int t = b / NPART, p = b - t * NPART;
    int lo = p * RNODE;
    int n = bcursor[b]; if (n > BCAP) n = BCAP;
    int gbase = bbase[b];
    const uint2* ep = bpair + (size_t)b * BCAP;
    __shared__ int hist[RNODE];
    __shared__ int scn[RNODE];
    __shared__ int stage[BCAP];
    int tid = threadIdx.x;
    hist[tid] = 0;
    __syncthreads();
    for (int i = tid; i < n; i += 512)
        atomicAdd(&hist[(int)ep[i].y - lo], 1);
    __syncthreads();
    scn[tid] = hist[tid];
    __syncthreads();
    for (int off = 1; off < RNODE; off <<= 1) {
        int v = (tid >= off) ? scn[tid - off] : 0;
        __syncthreads();
        scn[tid] += v;
        __syncthreads();
    }
    int ex = scn[tid] - hist[tid];
    int node = lo + tid;
    if (node < NN) offs[t * (NN + 1) + node] = gbase + ex;
    if (p == NPART - 1 && tid == 0) offs[t * (NN + 1) + NN] = EE;
    hist[tid] = ex;                  // reuse as per-node cursor
    __syncthreads();
    for (int i = tid; i < n; i += 512) {
        uint2 e = ep[i];
        int pos = atomicAdd(&hist[(int)e.y - lo], 1);
        stage[pos] = (int)e.x;
    }
    __syncthreads();
    int* so = srt + (size_t)t * EE + gbase;
    for (int i = tid; i < n; i += 512) so[i] = stage[i];
}

// ---------- fused edge attention (round-9 form: scalar decode, unroll 4) ----------
__device__ __forceinline__ float f8dot(u32x4 kv, const float* q)
{
    f32x2 c0 = cvtpk8<false>(kv[0]);
    f32x2 c1 = cvtpk8<true>(kv[0]);
    f32x2 c2 = cvtpk8<false>(kv[1]);
    f32x2 c3 = cvtpk8<true>(kv[1]);
    return q[0] * c0[0] + q[1] * c0[1] + q[2] * c1[0] + q[3] * c1[1] +
           q[4] * c2[0] + q[5] * c2[1] + q[6] * c3[0] + q[7] * c3[1];
}

__device__ __forceinline__ void f8acc(float p, u32x4 kv, float* a)
{
    f32x2 c0 = cvtpk8<false>(kv[2]);
    f32x2 c1 = cvtpk8<true>(kv[2]);
    f32x2 c2 = cvtpk8<false>(kv[3]);
    f32x2 c3 = cvtpk8<true>(kv[3]);
    a[0] += p * c0[0]; a[1] += p * c0[1];
    a[2] += p * c1[0]; a[3] += p * c1[1];
    a[4] += p * c2[0]; a[5] += p * c2[1];
    a[6] += p * c3[0]; a[7] += p * c3[1];
}

__global__ __launch_bounds__(256) void attn_k(
    const ushort* __restrict__ q_ws, const unsigned char* __restrict__ kv_ws,
    const int* __restrict__ offs, const int* __restrict__ srt,
    ushort* __restrict__ agg)
{
    int wid = blockIdx.x * 4 + (threadIdx.x >> 6);
    int lane = threadIdx.x & 63;
    int half = lane >> 5;
    int sub = lane & 31;
    int t = wid / NN;
    int node = wid - t * NN;

    const ushort* qp = q_ws + ((size_t)(t * NN + node)) * 256 + sub * 8;
    ushort8v qu = *(const ushort8v*)qp;
    float q[8];
#pragma unroll
    for (int i = 0; i < 8; ++i) q[i] = bf2f(qu[i]);

    int o0 = offs[t * (NN + 1) + node];
    int o1 = offs[t * (NN + 1) + node + 1];
    const int* sp = srt + (size_t)t * EE;
    const unsigned char* kvb = kv_ws + (size_t)t * NN * 512 + sub * 16;

    const float scale = 0.17677669529663689f;
    float zA = 0.f, zB = 0.f;
    float aA[8] = {0.f, 0.f, 0.f, 0.f, 0.f, 0.f, 0.f, 0.f};
    float aB[8] = {0.f, 0.f, 0.f, 0.f, 0.f, 0.f, 0.f, 0.f};

    int j = o0;
    for (; j + 4 <= o1; j += 4) {
        int s0 = sp[j + half];
        int s1 = sp[j + 2 + half];
        u32x4 kv0 = *(const u32x4*)(kvb + (size_t)s0 * 512);
        u32x4 kv1 = *(const u32x4*)(kvb + (size_t)s1 * 512);
        float d0 = f8dot(kv0, q);
        float d1 = f8dot(kv1, q);
        d0 += __shfl_xor(d0, 1); d1 += __shfl_xor(d1, 1);
        d0 += __shfl_xor(d0, 2); d1 += __shfl_xor(d1, 2);
        float p0 = __expf(d0 * scale);
        float p1 = __expf(d1 * scale);
        zA += p0; zB += p1;
        f8acc(p0, kv0, aA);
        f8acc(p1, kv1, aB);
    }
    for (; j < o1; j += 2) {
        int e = j + half;
        int valid = (e < o1) ? 1 : 0;
        int s0 = sp[valid ? e : j];
        u32x4 kv0 = *(const u32x4*)(kvb + (size_t)s0 * 512);
        float d0 = f8dot(kv0, q);
        d0 += __shfl_xor(d0, 1);
        d0 += __shfl_xor(d0, 2);
        float p0 = valid ? __expf(d0 * scale) : 0.f;
        zA += p0;
        f8acc(p0, kv0, aA);
    }

    float z = zA + zB;
    z += __shfl_xor(z, 32);
    float a[8];
#pragma unroll
    for (int i = 0; i < 8; ++i) {
        a[i] = aA[i] + aB[i];
        a[i] += __shfl_xor(a[i], 32);
    }

    if (half == 0) {
        float inv = (z > 0.f) ? 1.0f / z : 0.f;
        ushort8v r;
#pragma unroll
        for (int i = 0; i < 8; ++i) r[i] = f2bf(a[i] * inv);
        *(ushort8v*)(agg + ((size_t)(t * NN + node)) * 256 + sub * 8) = r;
    }
}

extern "C" void kernel_launch(void* const* d_in, const int* in_sizes, int n_in,
                              void* d_out, int out_size, void* d_ws, size_t ws_size,
                              hipStream_t stream)
{
    const float* x      = (const float*)d_in[0];
    const float* W_qkv  = (const float*)d_in[1];
    const float* b_qkv  = (const float*)d_in[2];
    const float* W_out  = (const float*)d_in[3];
    const float* b_out  = (const float*)d_in[4];
    const int* edge_src = (const int*)d_in[5];
    const int* edge_dst = (const int*)d_in[6];
    float* out = (float*)d_out;

    char* ws = (char*)d_ws;
    size_t off = 0;
    auto carve = [&](size_t bytes) {
        char* p = ws + off;
        off += (bytes + 255) & ~(size_t)255;
        return p;
    };
    ushort* xb    = (ushort*)carve((size_t)NN * DIM * 2);
    ushort* wqkvt = (ushort*)carve((size_t)1536 * 256 * 2);
    ushort* woutt = (ushort*)carve((size_t)TT * 256 * 256 * 2);
    ushort* q_ws  = (ushort*)carve((size_t)TT * NN * 256 * 2);
    unsigned char* kv_ws = (unsigned char*)carve((size_t)TT * NN * 512);
    ushort* aggb  = (ushort*)carve((size_t)TT * NN * 256 * 2);
    int* offs     = (int*)carve((size_t)TT * (NN + 1) * 4);
    int* srt      = (int*)carve((size_t)TT * EE * 4);
    uint2* bpair  = (uint2*)carve((size_t)TT * NPART * BCAP * 8);
    int* bcursor  = (int*)carve((size_t)TT * NPART * 4);
    int* bbase    = (int*)carve((size_t)TT * NPART * 4);

    (void)hipMemsetAsync(bcursor, 0, (size_t)TT * NPART * 4, stream);

    cvt_xout_k<<<(NN * 64 + 255) / 256, 256, 0, stream>>>(x, xb, out);
    cvt_w_k<<<(256 * 1536 + TT * 65536 + 255) / 256, 256, 0, stream>>>(W_qkv, W_out,
                                                                       wqkvt, woutt);

    gemm3_k<0><<<dim3(391, 12), 256, 0, stream>>>(xb, wqkvt, b_qkv, q_ws, kv_ws,
                                                  nullptr, NN);

    edge_bucket_k<<<TT * K1BLK, 256, 0, stream>>>(edge_dst, edge_src, bcursor, bpair);
    bucket_scan_k<<<1, 128, 0, stream>>>(bcursor, bbase);
    bucket_scatter_k<<<TT * NPART, 512, 0, stream>>>(bpair, bcursor, bbase, offs, srt);

    attn_k<<<(NN * TT) / 4, 256, 0, stream>>>(q_ws, kv_ws, offs, srt, aggb);

    gemm3_k<1><<<dim3(391, 4), 256, 0, stream>>>(aggb, woutt, b_out,
                                                 nullptr, nullptr, out, NN);
}

// Round 12
// 329.284 us; speedup vs baseline: 1.9301x; 1.0309x over previous
//
#include <hip/hip_runtime.h>

#define NN 50000
#define DIM 256
#define HH 8
#define TT 2
#define EE 800000
#define HDIM 32

#define NPART 98        // buckets per t, 512 nodes each
#define RNODE 512
#define BCAP 12288      // bucket capacity (mean 8192, +45 sigma)
#define K1CH 8192       // edges per edge_bucket_k block
#define K1BLK 98        // ceil(EE / K1CH)

typedef __attribute__((ext_vector_type(8))) short short8;
typedef __attribute__((ext_vector_type(8))) unsigned short ushort8v;
typedef __attribute__((ext_vector_type(4))) float f32x4;
typedef __attribute__((ext_vector_type(2))) float f32x2;
typedef __attribute__((ext_vector_type(4))) unsigned int u32x4;

typedef __attribute__((address_space(3))) unsigned int u32_lds;
typedef __attribute__((address_space(1))) const unsigned int u32_glb;

__device__ __forceinline__ float bf2f(ushort u) {
    return __uint_as_float(((unsigned)u) << 16);
}
__device__ __forceinline__ ushort f2bf(float f) {
    unsigned u = __float_as_uint(f);
    unsigned r = u + 0x7fffu + ((u >> 16) & 1u);
    return (ushort)(r >> 16);
}

// fp8 e4m3 packed decode (HW): bytes [0:1] (HI=false) or [2:3] (HI=true) of w
template <bool HI>
__device__ __forceinline__ f32x2 cvtpk8(unsigned w) {
    return __builtin_amdgcn_cvt_pk_f32_fp8((int)w, HI);
}

// ---------- fused convert: x -> bf16 xb AND out[:, 0:256] ----------
__global__ void cvt_xout_k(const float* __restrict__ x, ushort* __restrict__ xb,
                           float* __restrict__ out) {
    int i = blockIdx.x * blockDim.x + threadIdx.x;
    if (i < NN * 64) {
        int n = i >> 6;
        int c = i & 63;
        float4 v = ((const float4*)x)[i];
        ushort4 o;
        o.x = f2bf(v.x); o.y = f2bf(v.y); o.z = f2bf(v.z); o.w = f2bf(v.w);
        ((ushort4*)xb)[i] = o;
        *(float4*)(out + (size_t)n * 768 + c * 4) = v;
    }
}

// all weights transposed/converted in one launch
__global__ void cvt_w_k(const float* __restrict__ Wqkv, const float* __restrict__ Wout,
                        ushort* __restrict__ wqkvt, ushort* __restrict__ woutt) {
    int idx = blockIdx.x * blockDim.x + threadIdx.x;
    if (idx < 256 * 1536) {
        int k = idx / 1536;
        int nn = idx - k * 1536;
        wqkvt[nn * 256 + k] = f2bf(Wqkv[idx]);
    } else {
        int j = idx - 256 * 1536;
        if (j < TT * 65536) {
            int t = j >> 16;
            int r = j & 65535;
            int k = r >> 8;
            int nn = r & 255;
            woutt[t * 65536 + nn * 256 + k] = f2bf(Wout[t * 65536 + k * 256 + nn]);
        }
    }
}

// ---------- m97-style MFMA GEMM: 128x128 tile, BK=64, global_load_lds + XOR swizzle ----
// 1-D flat grid + bijective XCD swizzle (T1, m204): each XCD owns a contiguous
// wgid chunk; wgid = rowblock*NY + colblock so one XCD reuses its A row-panels
// from its own L2 (A fetched once device-wide), B (<1 MB) L2-resident per XCD.
template <int EPI>
__global__ __launch_bounds__(256) void gemm3_k(
    const ushort* __restrict__ A, const ushort* __restrict__ Bt,
    const float* __restrict__ bias,
    ushort* __restrict__ qo, unsigned char* __restrict__ kvo,
    float* __restrict__ outf, int M)
{
    __shared__ ushort As[128 * 64];
    __shared__ ushort Bs[128 * 64];
    const int tid = threadIdx.x;
    const int lane = tid & 63;
    const int w = tid >> 6;          // 4 waves: 2M x 2N
    const int wr = w >> 1, wc = w & 1;
    const int lr = lane & 15;
    const int lq = lane >> 4;

    constexpr int NY = (EPI == 0) ? 12 : 4;
    constexpr int NWG = 391 * NY;
    constexpr int qq = NWG / 8, rr8 = NWG % 8;
    int flat = blockIdx.x;
    int xcd = flat & 7;
    int idx = flat >> 3;
    int wgid = (xcd < rr8 ? xcd * (qq + 1) : rr8 * (qq + 1) + (xcd - rr8) * qq) + idx;
    int bx = wgid / NY;
    int by = wgid - bx * NY;
    const int m0 = bx * 128;

    int n0, col_base = 0, tsel = 0;
    if (EPI == 0) {
        n0 = by * 128;
    } else {
        tsel = by >> 1;
        n0 = (by & 1) * 128;
        col_base = 256 + tsel * 256;
    }
    const ushort* A_  = (EPI == 0) ? A  : A  + (size_t)tsel * NN * 256;
    const ushort* Bt_ = (EPI == 0) ? Bt : Bt + (size_t)tsel * 65536;
    const float* bias_ = (EPI == 0) ? bias : bias + tsel * 256;

    f32x4 acc[4][4];
#pragma unroll
    for (int mt = 0; mt < 4; ++mt)
#pragma unroll
        for (int nt = 0; nt < 4; ++nt) acc[mt][nt] = (f32x4){0.f, 0.f, 0.f, 0.f};

    for (int ks = 0; ks < 256; ks += 64) {
#pragma unroll
        for (int it = 0; it < 4; ++it) {
            int u = tid + it * 256;          // 0..1023: row=u>>3, slot=u&7
            int r = u >> 3, s = u & 7;
            int ss = (s ^ (r & 7)) << 3;     // pre-swizzled source slot (elements)
            const ushort* srcA = A_ + (size_t)(m0 + r) * 256 + ks + ss;
            __builtin_amdgcn_global_load_lds((u32_glb*)srcA,
                (u32_lds*)((char*)As + (u << 4)), 16, 0, 0);
            const ushort* srcB = Bt_ + (size_t)(n0 + r) * 256 + ks + ss;
            __builtin_amdgcn_global_load_lds((u32_glb*)srcB,
                (u32_lds*)((char*)Bs + (u << 4)), 16, 0, 0);
        }
        __syncthreads();

#pragma unroll
        for (int ku = 0; ku < 2; ++ku) {
            short8 a[4], b[4];
#pragma unroll
            for (int mt = 0; mt < 4; ++mt) {
                int row = wr * 64 + mt * 16 + lr;
                int s = ku * 4 + lq;
                a[mt] = *(const short8*)((const char*)As + row * 128 + (((s ^ (row & 7)) & 7) << 4));
            }
#pragma unroll
            for (int nt = 0; nt < 4; ++nt) {
                int row = wc * 64 + nt * 16 + lr;
                int s = ku * 4 + lq;
                b[nt] = *(const short8*)((const char*)Bs + row * 128 + (((s ^ (row & 7)) & 7) << 4));
            }
#pragma unroll
            for (int mt = 0; mt < 4; ++mt)
#pragma unroll
                for (int nt = 0; nt < 4; ++nt)
                    acc[mt][nt] = __builtin_amdgcn_mfma_f32_16x16x32_bf16(a[mt], b[nt], acc[mt][nt], 0, 0, 0);
        }
        __syncthreads();
    }

#pragma unroll
    for (int mt = 0; mt < 4; ++mt) {
        int rowb = m0 + wr * 64 + mt * 16 + (lq << 2);
#pragma unroll
        for (int nt = 0; nt < 4; ++nt) {
            int col = n0 + wc * 64 + nt * 16 + lr;
            float bv = bias_[col];
#pragma unroll
            for (int r2 = 0; r2 < 4; ++r2) {
                int rr = rowb + r2;
                if (rr < M) {
                    float val = acc[mt][nt][r2] + bv;
                    if (EPI == 0) {
                        int t = col / 768;
                        int rem = col - t * 768;
                        int h = rem / 96;
                        int rem2 = rem - h * 96;
                        int s3 = rem2 >> 5;
                        int hd = rem2 & 31;
                        int d = h * 32 + hd;
                        if (s3 == 0) {
                            qo[((size_t)(t * NN + rr)) * 256 + d] = f2bf(val);
                        } else {
                            unsigned by8 = ((unsigned)__builtin_amdgcn_cvt_pk_fp8_f32(val, val, 0, false)) & 0xffu;
                            size_t off = ((size_t)(t * NN + rr)) * 512 +
                                         ((size_t)(d >> 3) << 4) + (d & 7) + ((s3 == 2) ? 8 : 0);
                            kvo[off] = (unsigned char)by8;
                        }
                    } else {
                        outf[(size_t)rr * 768 + col_base + col] = val;
                    }
                }
            }
        }
    }
}

// ---------- bucket-partition CSR build ----------
__global__ __launch_bounds__(256) void edge_bucket_k(
    const int* __restrict__ dst, const int* __restrict__ src,
    int* __restrict__ bcursor, uint2* __restrict__ bpair)
{
    int t = blockIdx.x / K1BLK;
    int cb = blockIdx.x - t * K1BLK;
    int base = cb * K1CH;
    const int* dp = dst + (size_t)t * EE;
    const int* sp = src + (size_t)t * EE;
    __shared__ int bcnt[NPART];
    __shared__ int bbase_l[NPART];
    int tid = threadIdx.x;
    if (tid < NPART) bcnt[tid] = 0;
    __syncthreads();
    int lim = EE - base; if (lim > K1CH) lim = K1CH;
#pragma unroll
    for (int it = 0; it < K1CH / 1024; ++it) {
        int i = (it * 256 + tid) * 4;
        if (i < lim) {
            int4 d4 = *(const int4*)(dp + base + i);
            atomicAdd(&bcnt[d4.x >> 9], 1);
            atomicAdd(&bcnt[d4.y >> 9], 1);
            atomicAdd(&bcnt[d4.z >> 9], 1);
            atomicAdd(&bcnt[d4.w >> 9], 1);
        }
    }
    __syncthreads();
    if (tid < NPART)
        bbase_l[tid] = atomicAdd(&bcursor[t * NPART + tid], bcnt[tid]);
    __syncthreads();
    if (tid < NPART) bcnt[tid] = 0;   // reuse as local cursor
    __syncthreads();
#pragma unroll
    for (int it = 0; it < K1CH / 1024; ++it) {
        int i = (it * 256 + tid) * 4;
        if (i < lim) {
            int4 d4 = *(const int4*)(dp + base + i);
            int4 s4 = *(const int4*)(sp + base + i);
            int dd[4] = {d4.x, d4.y, d4.z, d4.w};
            int ss[4] = {s4.x, s4.y, s4.z, s4.w};
#pragma unroll
            for (int e = 0; e < 4; ++e) {
                int p = dd[e] >> 9;
                int pos = bbase_l[p] + atomicAdd(&bcnt[p], 1);
                if (pos < BCAP)
                    bpair[(size_t)(t * NPART + p) * BCAP + pos] =
                        make_uint2((unsigned)ss[e], (unsigned)dd[e]);
            }
        }
    }
}

__global__ __launch_bounds__(128) void bucket_scan_k(
    const int* __restrict__ bcursor, int* __restrict__ bbase)
{
    __shared__ int sh[TT][128];
    int tid = threadIdx.x;
    for (int t = 0; t < TT; ++t)
        sh[t][tid] = (tid < NPART) ? bcursor[t * NPART + tid] : 0;
    __syncthreads();
    for (int off = 1; off < 128; off <<= 1) {
        int v0 = (tid >= off) ? sh[0][tid - off] : 0;
        int v1 = (tid >= off) ? sh[1][tid - off] : 0;
        __syncthreads();
        sh[0][tid] += v0;
        sh[1][tid] += v1;
        __syncthreads();
    }
    for (int t = 0; t < TT; ++t)
        if (tid < NPART) bbase[t * NPART + tid] = (tid == 0) ? 0 : sh[t][tid - 1];
}

__global__ __launch_bounds__(512) void bucket_scatter_k(
    const uint2* __restrict__ bpair, const int* __restrict__ bcursor,
    const int* __restrict__ bbase, int* __restrict__ offs, int* __restrict__ srt)
{
    int b = blockIdx.x;              // 0..TT*NPART-1
    int t = b / NPART, p = b - t * NPART;
    int lo = p * RNODE;
    int n = bcursor[b]; if (n > BCAP) n = BCAP;
    int gbase = bbase[b];
    const uint2* ep = bpair + (size_t)b * BCAP;
    __shared__ int hist[RNODE];
    __shared__ int scn[RNODE];
    __shared__ int stage[BCAP];
    int tid = threadIdx.x;
    hist[tid] = 0;
    __syncthreads();
    for (int i = tid; i < n; i += 512)
        atomicAdd(&hist[(int)ep[i].y - lo], 1);
    __syncthreads();
    scn[tid] = hist[tid];
    __syncthreads();
    for (int off = 1; off < RNODE; off <<= 1) {
        int v = (tid >= off) ? scn[tid - off] : 0;
        __syncthreads();
        scn[tid] += v;
        __syncthreads();
    }
    int ex = scn[tid] - hist[tid];
    int node = lo + tid;
    if (node < NN) offs[t * (NN + 1) + node] = gbase + ex;
    if (p == NPART - 1 && tid == 0) offs[t * (NN + 1) + NN] = EE;
    hist[tid] = ex;                  // reuse as per-node cursor
    __syncthreads();
    for (int i = tid; i < n; i += 512) {
        uint2 e = ep[i];
        int pos = atomicAdd(&hist[(int)e.y - lo], 1);
        stage[pos] = (int)e.x;
    }
    __syncthreads();
    int* so = srt + (size_t)t * EE + gbase;
    for (int i = tid; i < n; i += 512) so[i] = stage[i];
}

// ---------- fused edge attention (scalar decode, unroll 4) ----------
__device__ __forceinline__ float f8dot(u32x4 kv, const float* q)
{
    f32x2 c0 = cvtpk8<false>(kv[0]);
    f32x2 c1 = cvtpk8<true>(kv[0]);
    f32x2 c2 = cvtpk8<false>(kv[1]);
    f32x2 c3 = cvtpk8<true>(kv[1]);
    return q[0] * c0[0] + q[1] * c0[1] + q[2] * c1[0] + q[3] * c1[1] +
           q[4] * c2[0] + q[5] * c2[1] + q[6] * c3[0] + q[7] * c3[1];
}

__device__ __forceinline__ void f8acc(float p, u32x4 kv, float* a)
{
    f32x2 c0 = cvtpk8<false>(kv[2]);
    f32x2 c1 = cvtpk8<true>(kv[2]);
    f32x2 c2 = cvtpk8<false>(kv[3]);
    f32x2 c3 = cvtpk8<true>(kv[3]);
    a[0] += p * c0[0]; a[1] += p * c0[1];
    a[2] += p * c1[0]; a[3] += p * c1[1];
    a[4] += p * c2[0]; a[5] += p * c2[1];
    a[6] += p * c3[0]; a[7] += p * c3[1];
}

__global__ __launch_bounds__(256) void attn_k(
    const ushort* __restrict__ q_ws, const unsigned char* __restrict__ kv_ws,
    const int* __restrict__ offs, const int* __restrict__ srt,
    ushort* __restrict__ agg)
{
    int wid = blockIdx.x * 4 + (threadIdx.x >> 6);
    int lane = threadIdx.x & 63;
    int half = lane >> 5;
    int sub = lane & 31;
    int t = wid / NN;
    int node = wid - t * NN;

    const ushort* qp = q_ws + ((size_t)(t * NN + node)) * 256 + sub * 8;
    ushort8v qu = *(const ushort8v*)qp;
    float q[8];
#pragma unroll
    for (int i = 0; i < 8; ++i) q[i] = bf2f(qu[i]);

    int o0 = offs[t * (NN + 1) + node];
    int o1 = offs[t * (NN + 1) + node + 1];
    const int* sp = srt + (size_t)t * EE;
    const unsigned char* kvb = kv_ws + (size_t)t * NN * 512 + sub * 16;

    const float scale = 0.17677669529663689f;
    float zA = 0.f, zB = 0.f;
    float aA[8] = {0.f, 0.f, 0.f, 0.f, 0.f, 0.f, 0.f, 0.f};
    float aB[8] = {0.f, 0.f, 0.f, 0.f, 0.f, 0.f, 0.f, 0.f};

    int j = o0;
    for (; j + 4 <= o1; j += 4) {
        int s0 = sp[j + half];
        int s1 = sp[j + 2 + half];
        u32x4 kv0 = *(const u32x4*)(kvb + (size_t)s0 * 512);
        u32x4 kv1 = *(const u32x4*)(kvb + (size_t)s1 * 512);
        float d0 = f8dot(kv0, q);
        float d1 = f8dot(kv1, q);
        d0 += __shfl_xor(d0, 1); d1 += __shfl_xor(d1, 1);
        d0 += __shfl_xor(d0, 2); d1 += __shfl_xor(d1, 2);
        float p0 = __expf(d0 * scale);
        float p1 = __expf(d1 * scale);
        zA += p0; zB += p1;
        f8acc(p0, kv0, aA);
        f8acc(p1, kv1, aB);
    }
    for (; j < o1; j += 2) {
        int e = j + half;
        int valid = (e < o1) ? 1 : 0;
        int s0 = sp[valid ? e : j];
        u32x4 kv0 = *(const u32x4*)(kvb + (size_t)s0 * 512);
        float d0 = f8dot(kv0, q);
        d0 += __shfl_xor(d0, 1);
        d0 += __shfl_xor(d0, 2);
        float p0 = valid ? __expf(d0 * scale) : 0.f;
        zA += p0;
        f8acc(p0, kv0, aA);
    }

    float z = zA + zB;
    z += __shfl_xor(z, 32);
    float a[8];
#pragma unroll
    for (int i = 0; i < 8; ++i) {
        a[i] = aA[i] + aB[i];
        a[i] += __shfl_xor(a[i], 32);
    }

    if (half == 0) {
        float inv = (z > 0.f) ? 1.0f / z : 0.f;
        ushort8v r;
#pragma unroll
        for (int i = 0; i < 8; ++i) r[i] = f2bf(a[i] * inv);
        *(ushort8v*)(agg + ((size_t)(t * NN + node)) * 256 + sub * 8) = r;
    }
}

extern "C" void kernel_launch(void* const* d_in, const int* in_sizes, int n_in,
                              void* d_out, int out_size, void* d_ws, size_t ws_size,
                              hipStream_t stream)
{
    const float* x      = (const float*)d_in[0];
    const float* W_qkv  = (const float*)d_in[1];
    const float* b_qkv  = (const float*)d_in[2];
    const float* W_out  = (const float*)d_in[3];
    const float* b_out  = (const float*)d_in[4];
    const int* edge_src = (const int*)d_in[5];
    const int* edge_dst = (const int*)d_in[6];
    float* out = (float*)d_out;

    char* ws = (char*)d_ws;
    size_t off = 0;
    auto carve = [&](size_t bytes) {
        char* p = ws + off;
        off += (bytes + 255) & ~(size_t)255;
        return p;
    };
    ushort* xb    = (ushort*)carve((size_t)NN * DIM * 2);
    ushort* wqkvt = (ushort*)carve((size_t)1536 * 256 * 2);
    ushort* woutt = (ushort*)carve((size_t)TT * 256 * 256 * 2);
    ushort* q_ws  = (ushort*)carve((size_t)TT * NN * 256 * 2);
    unsigned char* kv_ws = (unsigned char*)carve((size_t)TT * NN * 512);
    ushort* aggb  = (ushort*)carve((size_t)TT * NN * 256 * 2);
    int* offs     = (int*)carve((size_t)TT * (NN + 1) * 4);
    int* srt      = (int*)carve((size_t)TT * EE * 4);
    uint2* bpair  = (uint2*)carve((size_t)TT * NPART * BCAP * 8);
    int* bcursor  = (int*)carve((size_t)TT * NPART * 4);
    int* bbase    = (int*)carve((size_t)TT * NPART * 4);

    (void)hipMemsetAsync(bcursor, 0, (size_t)TT * NPART * 4, stream);

    cvt_xout_k<<<(NN * 64 + 255) / 256, 256, 0, stream>>>(x, xb, out);
    cvt_w_k<<<(256 * 1536 + TT * 65536 + 255) / 256, 256, 0, stream>>>(W_qkv, W_out,
                                                                       wqkvt, woutt);

    gemm3_k<0><<<391 * 12, 256, 0, stream>>>(xb, wqkvt, b_qkv, q_ws, kv_ws,
                                             nullptr, NN);

    edge_bucket_k<<<TT * K1BLK, 256, 0, stream>>>(edge_dst, edge_src, bcursor, bpair);
    bucket_scan_k<<<1, 128, 0, stream>>>(bcursor, bbase);
    bucket_scatter_k<<<TT * NPART, 512, 0, stream>>>(bpair, bcursor, bbase, offs, srt);

    attn_k<<<(NN * TT) / 4, 256, 0, stream>>>(q_ws, kv_ws, offs, srt, aggb);

    gemm3_k<1><<<391 * 4, 256, 0, stream>>>(aggb, woutt, b_out,
                                            nullptr, nullptr, out, NN);
}